// Round 2
// baseline (3193.527 us; speedup 1.0000x reference)
//
#include <hip/hip_runtime.h>
#include <hip/hip_bf16.h>

#define NTOT  300000
#define NNODE 50000
#define RPD   16
#define NREL  50
#define EMB   16
#define NC    10
#define EPSF  1e-6f

typedef const __hip_bfloat16* bf16p;

__device__ __forceinline__ float b2f(__hip_bfloat16 x){ return __bfloat162float(x); }

// unpack a uint holding 2 packed bf16 -> 2 floats (low half = elem 2k, high = 2k+1)
__device__ __forceinline__ void unpack2(unsigned u, float& a, float& b){
  a = __uint_as_float(u << 16);
  b = __uint_as_float(u & 0xffff0000u);
}

// generic scalar load: bf16-or-fp32 element i of array p
__device__ __forceinline__ float ldf(const void* p, int i, int bf){
  return bf ? b2f(((bf16p)p)[i]) : ((const float*)p)[i];
}

// ---- dtype detection: fp32 one-hot rows contain ONLY words 0x0 / 0x3F800000.
// bf16-packed one-hot has (1.0 @ even idx) -> word 0x00003F80. Scan 4096 words.
__global__ void k_detect(const unsigned* nraw, int* flag){
  __shared__ int bad;
  if(threadIdx.x == 0) bad = 0;
  __syncthreads();
  for(int i = threadIdx.x; i < 4096; i += 1024){
    unsigned w = nraw[i];
    if(w != 0u && w != 0x3F800000u) bad = 1;
  }
  __syncthreads();
  if(threadIdx.x == 0) *flag = bad;   // 1 => bf16 mode, 0 => fp32 mode
}

__global__ void k_zero(float* p, long n){
  long i = (long)blockIdx.x*blockDim.x + threadIdx.x;
  long stride = (long)gridDim.x*blockDim.x;
  for(; i < n; i += stride) p[i] = 0.f;
}

// softmax tables: T1/T2[rel][r] = softmax_r(Wl[rel][r] + bl[r])
__global__ void k_tables(const void* Wl1, const void* bl1, const void* Wl2, const void* bl2,
                         float* T1, float* T2, const int* flag){
  int bf = *flag;
  int i = threadIdx.x;
  const void* W = nullptr; const void* bl = nullptr; float* T = nullptr; int row = -1;
  if(i < NREL){ W = Wl1; bl = bl1; T = T1; row = i; }
  else if(i >= 64 && i < 64 + NREL){ W = Wl2; bl = bl2; T = T2; row = i - 64; }
  if(row >= 0){
    float v[RPD]; float m = -1e30f;
    for(int r = 0; r < RPD; r++){
      v[r] = ldf(W, row*RPD + r, bf) + ldf(bl, r, bf);
      m = fmaxf(m, v[r]);
    }
    float s = 0.f;
    for(int r = 0; r < RPD; r++){ v[r] = __expf(v[r] - m); s += v[r]; }
    float inv = 1.f / s;
    for(int r = 0; r < RPD; r++) T[row*RPD + r] = v[r] * inv;
  }
}

// argmax relation per edge + colsum/rowsum scatters (r=0 flood block-reduced)
__global__ __launch_bounds__(256) void k_sums(const void* nhots, const int* srow, const int* ocol,
    const float* T1, const float* T2, int* p, float* colsum, float* rowsum, const int* flag){
  __shared__ float lT1[NREL*RPD], lT2[NREL*RPD];
  __shared__ float sc[4], sr[4];
  int bf = *flag;
  int tid = threadIdx.x;
  for(int i = tid; i < NREL*RPD; i += 256){ lT1[i] = T1[i]; lT2[i] = T2[i]; }
  __syncthreads();
  int t = blockIdx.x*256 + tid;
  float c0 = 0.f, r0 = 0.f;
  if(t < NTOT){
    int pt = 0; float best = -1e30f;
    if(bf){
      const unsigned* row = (const unsigned*)nhots + (size_t)t*(NREL/2);  // 25 words
      for(int k = 0; k < NREL/2; k++){
        float a, b2; unpack2(row[k], a, b2);
        if(a  > best){ best = a;  pt = 2*k;   }
        if(b2 > best){ best = b2; pt = 2*k+1; }
      }
    } else {
      const float* row = (const float*)nhots + (size_t)t*NREL;
      for(int k = 0; k < NREL; k++){
        float v = row[k];
        if(v > best){ best = v; pt = k; }
      }
    }
    p[t] = pt;
    int ot = ocol[t], st = srow[t];
    const float* t1 = lT1 + pt*RPD;
    const float* t2 = lT2 + pt*RPD;
    c0 = t1[0]; r0 = t2[0];
    for(int r = 1; r < RPD; r++){
      atomicAdd(&colsum[ot*r], t1[r]);
      atomicAdd(&rowsum[st*r], t2[r]);
    }
  }
  for(int off = 32; off > 0; off >>= 1){
    c0 += __shfl_down(c0, off);
    r0 += __shfl_down(r0, off);
  }
  int lane = tid & 63, wid = tid >> 6;
  if(lane == 0){ sc[wid] = c0; sr[wid] = r0; }
  __syncthreads();
  if(tid == 0){
    atomicAdd(&colsum[0], sc[0]+sc[1]+sc[2]+sc[3]);
    atomicAdd(&rowsum[0], sr[0]+sr[1]+sr[2]+sr[3]);
  }
}

// layer1 spmm: h[s] += sum_r (T1[p][r]/max(colsum[o*r],eps)) * W1[o*r][:]
__global__ __launch_bounds__(256) void k_h(const int* srow, const int* ocol, const int* p,
    const float* T1, const float* colsum, const void* W1, float* h, const int* flag){
  __shared__ float lT1[NREL*RPD];
  int bf = *flag;
  int tid = threadIdx.x;
  for(int i = tid; i < NREL*RPD; i += 256) lT1[i] = T1[i];
  __syncthreads();
  int t = blockIdx.x*256 + tid;
  if(t >= NTOT) return;
  int pt = p[t], ot = ocol[t], st = srow[t];
  const float* t1 = lT1 + pt*RPD;
  float acc[EMB];
  #pragma unroll
  for(int j = 0; j < EMB; j++) acc[j] = 0.f;
  for(int r = 0; r < RPD; r++){
    int c = ot * r;
    float w = t1[r] / fmaxf(colsum[c], EPSF);
    float f[16];
    if(bf){
      const uint4* W1v = (const uint4*)W1;  // 16 bf16 per row = 2 uint4
      uint4 q0 = W1v[(size_t)c*2], q1 = W1v[(size_t)c*2 + 1];
      unpack2(q0.x, f[0],  f[1]);  unpack2(q0.y, f[2],  f[3]);
      unpack2(q0.z, f[4],  f[5]);  unpack2(q0.w, f[6],  f[7]);
      unpack2(q1.x, f[8],  f[9]);  unpack2(q1.y, f[10], f[11]);
      unpack2(q1.z, f[12], f[13]); unpack2(q1.w, f[14], f[15]);
    } else {
      const float4* W1v = (const float4*)W1;  // 16 fp32 per row = 4 float4
      float4 a = W1v[(size_t)c*4], b = W1v[(size_t)c*4+1],
             cc = W1v[(size_t)c*4+2], d = W1v[(size_t)c*4+3];
      f[0]=a.x; f[1]=a.y; f[2]=a.z; f[3]=a.w;
      f[4]=b.x; f[5]=b.y; f[6]=b.z; f[7]=b.w;
      f[8]=cc.x; f[9]=cc.y; f[10]=cc.z; f[11]=cc.w;
      f[12]=d.x; f[13]=d.y; f[14]=d.z; f[15]=d.w;
    }
    #pragma unroll
    for(int j = 0; j < EMB; j++) acc[j] += w * f[j];
  }
  float* hp = h + (size_t)st*EMB;
  #pragma unroll
  for(int j = 0; j < EMB; j++) atomicAdd(&hp[j], acc[j]);
}

__global__ void k_hfin(float* h, const void* bias1, const int* flag){
  int bf = *flag;
  int i = blockIdx.x*blockDim.x + threadIdx.x;
  if(i < NNODE*EMB) h[i] = fmaxf(h[i] + ldf(bias1, i & (EMB-1), bf), 0.f);
}

// layer2 fused: logits[v%n] += (T2[p][r]/max(rowsum[v],eps)) * (W2[v/n]^T h[o]),  v=s*r
// r=0 flood: block-reduce sum_t T2[p][0]*h[o[t]] into hacc0 (scaled in k_final)
__global__ __launch_bounds__(256) void k_logits(const int* srow, const int* ocol, const int* p,
    const float* T2, const float* rowsum, const float* h, const void* W2,
    float* logitsf, float* hacc0, const int* flag){
  __shared__ float lT2[NREL*RPD];
  __shared__ float lW2[RPD*EMB*NC];
  __shared__ float red[4][EMB];
  int bf = *flag;
  int tid = threadIdx.x;
  for(int i = tid; i < NREL*RPD; i += 256) lT2[i] = T2[i];
  for(int i = tid; i < RPD*EMB*NC; i += 256) lW2[i] = ldf(W2, i, bf);
  __syncthreads();
  int t = blockIdx.x*256 + tid;
  bool act = (t < NTOT);
  float hv[EMB];
  float u0 = 0.f;
  int pt = 0, st = 0;
  if(act){
    pt = p[t]; st = srow[t];
    int ot = ocol[t];
    const float4* hp = (const float4*)(h + (size_t)ot*EMB);
    float4 a = hp[0], b = hp[1], c = hp[2], d = hp[3];
    hv[0]=a.x; hv[1]=a.y; hv[2]=a.z; hv[3]=a.w;
    hv[4]=b.x; hv[5]=b.y; hv[6]=b.z; hv[7]=b.w;
    hv[8]=c.x; hv[9]=c.y; hv[10]=c.z; hv[11]=c.w;
    hv[12]=d.x; hv[13]=d.y; hv[14]=d.z; hv[15]=d.w;
    u0 = lT2[pt*RPD];
  } else {
    #pragma unroll
    for(int j = 0; j < EMB; j++) hv[j] = 0.f;
  }
  if(act){
    for(int r = 1; r < RPD; r++){
      int v = st * r;
      float scale = lT2[pt*RPD + r] / fmaxf(rowsum[v], EPSF);
      int rpi = v / NNODE;
      int npi = v - rpi*NNODE;
      const float* w2 = lW2 + rpi*EMB*NC;
      #pragma unroll
      for(int cc = 0; cc < NC; cc++){
        float g = 0.f;
        #pragma unroll
        for(int j = 0; j < EMB; j++) g += w2[j*NC + cc] * hv[j];
        atomicAdd(&logitsf[npi*NC + cc], scale * g);
      }
    }
  }
  #pragma unroll
  for(int j = 0; j < EMB; j++){
    float x = act ? u0 * hv[j] : 0.f;
    for(int off = 32; off > 0; off >>= 1) x += __shfl_down(x, off);
    if((tid & 63) == 0) red[tid >> 6][j] = x;
  }
  __syncthreads();
  if(tid < EMB) atomicAdd(&hacc0[tid], red[0][tid]+red[1][tid]+red[2][tid]+red[3][tid]);
}

// bias2 + row-0 fix + store (dtype-adaptive)
__global__ void k_final(const float* logitsf, const void* bias2, const void* W2,
    const float* hacc0, const float* rowsum, void* out, const int* flag){
  int bf = *flag;
  int i = blockIdx.x*blockDim.x + threadIdx.x;
  if(i >= NNODE*NC) return;
  int c = i % NC;
  float val = logitsf[i] + ldf(bias2, c, bf);
  if(i < NC){  // n'==0 row gets the r=0 flood contribution: W2[0]^T hacc0 / rowsum[0]
    float g = 0.f;
    #pragma unroll
    for(int j = 0; j < EMB; j++) g += ldf(W2, j*NC + c, bf) * hacc0[j];
    val += g / fmaxf(rowsum[0], EPSF);
  }
  if(bf) ((__hip_bfloat16*)out)[i] = __float2bfloat16(val);
  else   ((float*)out)[i] = val;
}

extern "C" void kernel_launch(void* const* d_in, const int* in_sizes, int n_in,
                              void* d_out, int out_size, void* d_ws, size_t ws_size,
                              hipStream_t stream){
  const void* nhots = d_in[0];
  const int* hrow = (const int*)d_in[1];   // hrow[t<NT] = s[t]
  const int* vcol = (const int*)d_in[4];   // vcol[t<NT] = o[t]
  const void* Wl1 = d_in[5];
  const void* bl1 = d_in[6];
  const void* Wl2 = d_in[7];
  const void* bl2 = d_in[8];
  const void* W1  = d_in[9];
  const void* bias1 = d_in[10];
  const void* W2  = d_in[11];
  const void* bias2 = d_in[12];

  float* ws = (float*)d_ws;
  int*   flag    = (int*)ws;             // 16 floats reserved
  float* T1      = ws + 16;              // 800
  float* T2      = T1 + 800;             // 800
  float* colsum  = T2 + 800;             // 800000
  float* rowsum  = colsum + 800000;      // 800000
  float* h       = rowsum + 800000;      // 800000
  float* logitsf = h + 800000;           // 500000
  float* hacc0   = logitsf + 500000;     // 16
  int*   p       = (int*)(hacc0 + 16);   // 300000

  k_detect<<<1, 1024, 0, stream>>>((const unsigned*)nhots, flag);
  const long nzero = 800000L*3 + 500000 + 16;  // colsum..hacc0 contiguous
  k_zero<<<2048, 256, 0, stream>>>(colsum, nzero);
  k_tables<<<1, 128, 0, stream>>>(Wl1, bl1, Wl2, bl2, T1, T2, flag);

  const int nblk = (NTOT + 255) / 256;
  k_sums<<<nblk, 256, 0, stream>>>(nhots, hrow, vcol, T1, T2, p, colsum, rowsum, flag);
  k_h<<<nblk, 256, 0, stream>>>(hrow, vcol, p, T1, colsum, W1, h, flag);
  k_hfin<<<(NNODE*EMB + 255)/256, 256, 0, stream>>>(h, bias1, flag);
  k_logits<<<nblk, 256, 0, stream>>>(hrow, vcol, p, T2, rowsum, h, W2, logitsf, hacc0, flag);
  k_final<<<(NNODE*NC + 255)/256, 256, 0, stream>>>(logitsf, bias2, W2, hacc0, rowsum, flag ? (void*)d_out : (void*)d_out, flag);
}

// Round 3
// 1282.938 us; speedup vs baseline: 2.4892x; 2.4892x over previous
//
#include <hip/hip_runtime.h>
#include <hip/hip_bf16.h>

#define NTOT  300000
#define NNODE 50000
#define RPD   16
#define NREL  50
#define EMB   16
#define NC    10
#define EPSF  1e-6f

typedef const __hip_bfloat16* bf16p;

__device__ __forceinline__ float b2f(__hip_bfloat16 x){ return __bfloat162float(x); }

// unpack a uint holding 2 packed bf16 -> 2 floats (low half = elem 2k, high = 2k+1)
__device__ __forceinline__ void unpack2(unsigned u, float& a, float& b){
  a = __uint_as_float(u << 16);
  b = __uint_as_float(u & 0xffff0000u);
}

// generic scalar load: bf16-or-fp32 element i of array p
__device__ __forceinline__ float ldf(const void* p, int i, int bf){
  return bf ? b2f(((bf16p)p)[i]) : ((const float*)p)[i];
}

// ---- dtype detection: fp32 one-hot rows contain ONLY words 0x0 / 0x3F800000.
__global__ void k_detect(const unsigned* nraw, int* flag){
  __shared__ int bad;
  if(threadIdx.x == 0) bad = 0;
  __syncthreads();
  for(int i = threadIdx.x; i < 4096; i += 1024){
    unsigned w = nraw[i];
    if(w != 0u && w != 0x3F800000u) bad = 1;
  }
  __syncthreads();
  if(threadIdx.x == 0) *flag = bad;   // 1 => bf16 mode, 0 => fp32 mode
}

__global__ void k_zero(float* p, long n){
  long i = (long)blockIdx.x*blockDim.x + threadIdx.x;
  long stride = (long)gridDim.x*blockDim.x;
  for(; i < n; i += stride) p[i] = 0.f;
}

// softmax tables: T1/T2[rel][r] = softmax_r(Wl[rel][r] + bl[r])
__global__ void k_tables(const void* Wl1, const void* bl1, const void* Wl2, const void* bl2,
                         float* T1, float* T2, const int* flag){
  int bf = *flag;
  int i = threadIdx.x;
  const void* W = nullptr; const void* bl = nullptr; float* T = nullptr; int row = -1;
  if(i < NREL){ W = Wl1; bl = bl1; T = T1; row = i; }
  else if(i >= 64 && i < 64 + NREL){ W = Wl2; bl = bl2; T = T2; row = i - 64; }
  if(row >= 0){
    float v[RPD]; float m = -1e30f;
    for(int r = 0; r < RPD; r++){
      v[r] = ldf(W, row*RPD + r, bf) + ldf(bl, r, bf);
      m = fmaxf(m, v[r]);
    }
    float s = 0.f;
    for(int r = 0; r < RPD; r++){ v[r] = __expf(v[r] - m); s += v[r]; }
    float inv = 1.f / s;
    for(int r = 0; r < RPD; r++) T[row*RPD + r] = v[r] * inv;
  }
}

// argmax relation per edge + colsum/rowsum scatters (r=0 flood block-reduced)
// + source-degree histogram for CSR
__global__ __launch_bounds__(256) void k_sums(const void* nhots, const int* srow, const int* ocol,
    const float* T1, const float* T2, int* p, float* colsum, float* rowsum,
    int* cnt, const int* flag){
  __shared__ float lT1[NREL*RPD], lT2[NREL*RPD];
  __shared__ float sc[4], sr[4];
  int bf = *flag;
  int tid = threadIdx.x;
  for(int i = tid; i < NREL*RPD; i += 256){ lT1[i] = T1[i]; lT2[i] = T2[i]; }
  __syncthreads();
  int t = blockIdx.x*256 + tid;
  float c0 = 0.f, r0 = 0.f;
  if(t < NTOT){
    int pt = 0; float best = -1e30f;
    if(bf){
      const unsigned* row = (const unsigned*)nhots + (size_t)t*(NREL/2);  // 25 words
      for(int k = 0; k < NREL/2; k++){
        float a, b2; unpack2(row[k], a, b2);
        if(a  > best){ best = a;  pt = 2*k;   }
        if(b2 > best){ best = b2; pt = 2*k+1; }
      }
    } else {
      const float* row = (const float*)nhots + (size_t)t*NREL;
      for(int k = 0; k < NREL; k++){
        float v = row[k];
        if(v > best){ best = v; pt = k; }
      }
    }
    p[t] = pt;
    int ot = ocol[t], st = srow[t];
    atomicAdd(&cnt[st], 1);
    const float* t1 = lT1 + pt*RPD;
    const float* t2 = lT2 + pt*RPD;
    c0 = t1[0]; r0 = t2[0];
    for(int r = 1; r < RPD; r++){
      atomicAdd(&colsum[ot*r], t1[r]);
      atomicAdd(&rowsum[st*r], t2[r]);
    }
  }
  for(int off = 32; off > 0; off >>= 1){
    c0 += __shfl_down(c0, off);
    r0 += __shfl_down(r0, off);
  }
  int lane = tid & 63, wid = tid >> 6;
  if(lane == 0){ sc[wid] = c0; sr[wid] = r0; }
  __syncthreads();
  if(tid == 0){
    atomicAdd(&colsum[0], sc[0]+sc[1]+sc[2]+sc[3]);
    atomicAdd(&rowsum[0], sr[0]+sr[1]+sr[2]+sr[3]);
  }
}

// exclusive scan of cnt[NNODE] -> start[NNODE+1]; cursor = copy of start
#define SCHUNK 49  // 1024*49 >= 50000
__global__ __launch_bounds__(1024) void k_scan(const int* cnt, int* start, int* cursor){
  __shared__ int ssum[1024];
  int tid = threadIdx.x;
  int base = tid * SCHUNK;
  int local = 0;
  for(int i = 0; i < SCHUNK; i++){ int idx = base + i; if(idx < NNODE) local += cnt[idx]; }
  ssum[tid] = local; __syncthreads();
  for(int off = 1; off < 1024; off <<= 1){
    int v = (tid >= off) ? ssum[tid - off] : 0;
    __syncthreads();
    ssum[tid] += v;
    __syncthreads();
  }
  int run = (tid == 0) ? 0 : ssum[tid - 1];
  for(int i = 0; i < SCHUNK; i++){
    int idx = base + i;
    if(idx < NNODE){ start[idx] = run; cursor[idx] = run; run += cnt[idx]; }
  }
  if(tid == 1023) start[NNODE] = run;  // chunks >= 1021 are empty: run == total
}

__global__ void k_fill(const int* srow, int* cursor, int* eidx){
  int t = blockIdx.x*256 + threadIdx.x;
  if(t < NTOT){
    int s = srow[t];
    int pos = atomicAdd(&cursor[s], 1);
    eidx[pos] = t;
  }
}

// layer1, wave-per-source gather: h[s] = relu(bias1 + sum_e sum_r (T1[p][r]/colsum[o*r])*W1[o*r])
// lane l: r = l>>2 owns pattern, q = l&3 owns emb quad. No atomics.
__global__ __launch_bounds__(256) void k_h_csr(const int* start, const int* eidx,
    const int* ocol, const int* p, const float* T1, const float* colsum,
    const void* W1, const void* bias1, float* h, const int* flag){
  __shared__ float lT1[NREL*RPD];
  int bf = *flag;
  int tid = threadIdx.x;
  for(int i = tid; i < NREL*RPD; i += 256) lT1[i] = T1[i];
  __syncthreads();
  int wave = tid >> 6, lane = tid & 63;
  int s = blockIdx.x*4 + wave;           // grid exactly covers NNODE
  int r = lane >> 2, q = lane & 3;
  float4 acc = {0.f, 0.f, 0.f, 0.f};
  int e0 = start[s], e1 = start[s+1];
  for(int e = e0; e < e1; e++){
    int t = eidx[e];
    int o = ocol[t], pt = p[t];
    int c = o * r;
    float w = lT1[pt*RPD + r] / fmaxf(colsum[c], EPSF);
    float4 f;
    if(bf){
      uint2 u = *((const uint2*)((const char*)W1 + (size_t)c*32) + q);
      unpack2(u.x, f.x, f.y); unpack2(u.y, f.z, f.w);
    } else {
      f = ((const float4*)W1)[(size_t)c*4 + q];
    }
    acc.x += w*f.x; acc.y += w*f.y; acc.z += w*f.z; acc.w += w*f.w;
  }
  // reduce across the 16 r-lanes (stride 4)
  for(int m = 4; m < 64; m <<= 1){
    acc.x += __shfl_xor(acc.x, m); acc.y += __shfl_xor(acc.y, m);
    acc.z += __shfl_xor(acc.z, m); acc.w += __shfl_xor(acc.w, m);
  }
  if(r == 0){
    float4 o4;
    o4.x = fmaxf(acc.x + ldf(bias1, q*4+0, bf), 0.f);
    o4.y = fmaxf(acc.y + ldf(bias1, q*4+1, bf), 0.f);
    o4.z = fmaxf(acc.z + ldf(bias1, q*4+2, bf), 0.f);
    o4.w = fmaxf(acc.w + ldf(bias1, q*4+3, bf), 0.f);
    ((float4*)h)[(size_t)s*4 + q] = o4;
  }
}

// layer2, wave-per-source: E[r] = sum_e T2[p][r]*h[o]; for r>=1:
// logits[(s*r)%n] += (W2[(s*r)/n]^T E[r]) / rowsum[s*r]   (150 atomics/source)
// r=0: block-reduce E[0] into 64-striped hacc0
__global__ __launch_bounds__(256) void k_logits_csr(const int* start, const int* eidx,
    const int* ocol, const int* p, const float* T2, const float* rowsum,
    const float* h, const void* W2, float* logitsf, float* hacc0, const int* flag){
  __shared__ float lT2[NREL*RPD];
  __shared__ float lW2[RPD*EMB*NC];
  __shared__ float sred[4][16];
  int bf = *flag;
  int tid = threadIdx.x;
  for(int i = tid; i < NREL*RPD; i += 256) lT2[i] = T2[i];
  for(int i = tid; i < RPD*EMB*NC; i += 256) lW2[i] = ldf(W2, i, bf);
  __syncthreads();
  int wave = tid >> 6, lane = tid & 63;
  int s = blockIdx.x*4 + wave;
  int r = lane >> 2, q = lane & 3;
  float4 E = {0.f, 0.f, 0.f, 0.f};
  int e0 = start[s], e1 = start[s+1];
  for(int e = e0; e < e1; e++){
    int t = eidx[e];
    int o = ocol[t], pt = p[t];
    float sc = lT2[pt*RPD + r];
    float4 hf = ((const float4*)h)[(size_t)o*4 + q];
    E.x += sc*hf.x; E.y += sc*hf.y; E.z += sc*hf.z; E.w += sc*hf.w;
  }
  if(r == 0){
    sred[wave][q*4+0] = E.x; sred[wave][q*4+1] = E.y;
    sred[wave][q*4+2] = E.z; sred[wave][q*4+3] = E.w;
  }
  __syncthreads();
  if(tid < 16){
    float v = sred[0][tid] + sred[1][tid] + sred[2][tid] + sred[3][tid];
    atomicAdd(&hacc0[(blockIdx.x & 63)*16 + tid], v);
  }
  if(r > 0 && e1 > e0){
    int v = s * r;
    float inv = 1.f / fmaxf(rowsum[v], EPSF);
    int rpi = v / NNODE;
    int npi = v - rpi*NNODE;
    const float* w2 = lW2 + rpi*EMB*NC + q*4*NC;
    float g[NC];
    #pragma unroll
    for(int c = 0; c < NC; c++)
      g[c] = w2[c]*E.x + w2[NC+c]*E.y + w2[2*NC+c]*E.z + w2[3*NC+c]*E.w;
    #pragma unroll
    for(int c = 0; c < NC; c++){
      g[c] += __shfl_xor(g[c], 1);
      g[c] += __shfl_xor(g[c], 2);
    }
    if(q == 0){
      float* lp = logitsf + (size_t)npi*NC;
      #pragma unroll
      for(int c = 0; c < NC; c++) atomicAdd(&lp[c], inv*g[c]);
    }
  }
}

// bias2 + row-0 fix (sum hacc0 stripes) + store
__global__ void k_final(const float* logitsf, const void* bias2, const void* W2,
    const float* hacc0, const float* rowsum, void* out, const int* flag){
  int bf = *flag;
  int i = blockIdx.x*blockDim.x + threadIdx.x;
  if(i >= NNODE*NC) return;
  int c = i % NC;
  float val = logitsf[i] + ldf(bias2, c, bf);
  if(i < NC){
    float inv = 1.f / fmaxf(rowsum[0], EPSF);
    float g = 0.f;
    for(int j = 0; j < EMB; j++){
      float hj = 0.f;
      for(int k = 0; k < 64; k++) hj += hacc0[k*16 + j];
      g += ldf(W2, j*NC + c, bf) * hj;
    }
    val += inv * g;
  }
  if(bf) ((__hip_bfloat16*)out)[i] = __float2bfloat16(val);
  else   ((float*)out)[i] = val;
}

extern "C" void kernel_launch(void* const* d_in, const int* in_sizes, int n_in,
                              void* d_out, int out_size, void* d_ws, size_t ws_size,
                              hipStream_t stream){
  const void* nhots = d_in[0];
  const int* hrow = (const int*)d_in[1];   // hrow[t<NT] = s[t]
  const int* vcol = (const int*)d_in[4];   // vcol[t<NT] = o[t]
  const void* Wl1 = d_in[5];
  const void* bl1 = d_in[6];
  const void* Wl2 = d_in[7];
  const void* bl2 = d_in[8];
  const void* W1  = d_in[9];
  const void* bias1 = d_in[10];
  const void* W2  = d_in[11];
  const void* bias2 = d_in[12];

  float* ws = (float*)d_ws;
  int*   flag    = (int*)ws;                  // [0, 16)
  float* T1      = ws + 16;                   // 800
  float* T2      = T1 + 800;                  // 800
  float* colsum  = T2 + 800;                  // 800000  -- zero region start
  float* rowsum  = colsum + 800000;           // 800000
  float* logitsf = rowsum + 800000;           // 500000
  float* hacc0   = logitsf + 500000;          // 1024 (64 stripes x 16)
  int*   cnt     = (int*)(hacc0 + 1024);      // 50000   -- zero region end
  float* h       = (float*)(cnt + 50000);     // 800000
  int*   p       = (int*)(h + 800000);        // 300000
  int*   startA  = p + 300000;                // 50001
  int*   cursor  = startA + 50001;            // 50000
  int*   eidx    = cursor + 50000;            // 300000

  const long nzero = 800000L + 800000 + 500000 + 1024 + 50000;  // colsum..cnt contiguous
  k_detect<<<1, 1024, 0, stream>>>((const unsigned*)nhots, flag);
  k_zero<<<2048, 256, 0, stream>>>(colsum, nzero);
  k_tables<<<1, 128, 0, stream>>>(Wl1, bl1, Wl2, bl2, T1, T2, flag);

  const int nblk = (NTOT + 255) / 256;
  k_sums<<<nblk, 256, 0, stream>>>(nhots, hrow, vcol, T1, T2, p, colsum, rowsum, cnt, flag);
  k_scan<<<1, 1024, 0, stream>>>(cnt, startA, cursor);
  k_fill<<<nblk, 256, 0, stream>>>(hrow, cursor, eidx);

  const int nsb = NNODE / 4;  // 12500 blocks, 4 waves (sources) each
  k_h_csr<<<nsb, 256, 0, stream>>>(startA, eidx, vcol, p, T1, colsum, W1, bias1, h, flag);
  k_logits_csr<<<nsb, 256, 0, stream>>>(startA, eidx, vcol, p, T2, rowsum, h, W2, logitsf, hacc0, flag);
  k_final<<<(NNODE*NC + 255)/256, 256, 0, stream>>>(logitsf, bias2, W2, hacc0, rowsum, d_out, flag);
}

// Round 4
// 818.160 us; speedup vs baseline: 3.9033x; 1.5681x over previous
//
#include <hip/hip_runtime.h>
#include <hip/hip_bf16.h>
#include <stdint.h>

#define NTOT  300000
#define NNODE 50000
#define RPD   16
#define NREL  50
#define EMB   16
#define NC    10
#define EPSF  1e-6f
#define NSB   12500   // blocks of 4 waves; 4 nodes/block covers NNODE

typedef const __hip_bfloat16* bf16p;

__device__ __forceinline__ float b2f(__hip_bfloat16 x){ return __bfloat162float(x); }

__device__ __forceinline__ void unpack2(unsigned u, float& a, float& b){
  a = __uint_as_float(u << 16);
  b = __uint_as_float(u & 0xffff0000u);
}

__device__ __forceinline__ float ldf(const void* p, int i, int bf){
  return bf ? b2f(((bf16p)p)[i]) : ((const float*)p)[i];
}

// ---- dtype detection: fp32 one-hot rows contain ONLY words 0x0 / 0x3F800000.
__global__ void k_detect(const unsigned* nraw, int* flag){
  __shared__ int bad;
  if(threadIdx.x == 0) bad = 0;
  __syncthreads();
  for(int i = threadIdx.x; i < 4096; i += 1024){
    unsigned w = nraw[i];
    if(w != 0u && w != 0x3F800000u) bad = 1;
  }
  __syncthreads();
  if(threadIdx.x == 0) *flag = bad;   // 1 => bf16 mode, 0 => fp32 mode
}

__global__ void k_zero(float* p, long n){
  long i = (long)blockIdx.x*blockDim.x + threadIdx.x;
  long stride = (long)gridDim.x*blockDim.x;
  for(; i < n; i += stride) p[i] = 0.f;
}

// softmax tables: T1/T2[rel][r] = softmax_r(Wl[rel][r] + bl[r])
__global__ void k_tables(const void* Wl1, const void* bl1, const void* Wl2, const void* bl2,
                         float* T1, float* T2, const int* flag){
  int bf = *flag;
  int i = threadIdx.x;
  const void* W = nullptr; const void* bl = nullptr; float* T = nullptr; int row = -1;
  if(i < NREL){ W = Wl1; bl = bl1; T = T1; row = i; }
  else if(i >= 64 && i < 64 + NREL){ W = Wl2; bl = bl2; T = T2; row = i - 64; }
  if(row >= 0){
    float v[RPD]; float m = -1e30f;
    for(int r = 0; r < RPD; r++){
      v[r] = ldf(W, row*RPD + r, bf) + ldf(bl, r, bf);
      m = fmaxf(m, v[r]);
    }
    float s = 0.f;
    for(int r = 0; r < RPD; r++){ v[r] = __expf(v[r] - m); s += v[r]; }
    float inv = 1.f / s;
    for(int r = 0; r < RPD; r++) T[row*RPD + r] = v[r] * inv;
  }
}

// argmax relation per edge + degree histograms for both CSRs
__global__ __launch_bounds__(256) void k_argmax(const void* nhots, const int* srow, const int* ocol,
    int* p, int* cnt_s, int* cnt_o, const int* flag){
  int bf = *flag;
  int t = blockIdx.x*256 + threadIdx.x;
  if(t >= NTOT) return;
  int pt = 0; float best = -1e30f;
  if(bf){
    const unsigned* row = (const unsigned*)nhots + (size_t)t*(NREL/2);  // 25 words
    for(int k = 0; k < NREL/2; k++){
      float a, b; unpack2(row[k], a, b);
      if(a > best){ best = a; pt = 2*k;   }
      if(b > best){ best = b; pt = 2*k+1; }
    }
  } else {
    const uint2* row = (const uint2*)((const float*)nhots + (size_t)t*NREL);  // 25 x 8B (8B-aligned: 200%8==0)
    for(int k = 0; k < NREL/2; k++){
      uint2 u = row[k];
      float a = __uint_as_float(u.x), b = __uint_as_float(u.y);
      if(a > best){ best = a; pt = 2*k;   }
      if(b > best){ best = b; pt = 2*k+1; }
    }
  }
  p[t] = pt;
  atomicAdd(&cnt_s[srow[t]], 1);
  atomicAdd(&cnt_o[ocol[t]], 1);
}

// two independent single-block exclusive scans (block 0: s-side, block 1: o-side)
#define SCHUNK 49  // 1024*49 >= 50000
__global__ __launch_bounds__(1024) void k_scan2(const int* cnt_s, int* start_s, int* cursor_s,
                                                const int* cnt_o, int* start_o, int* cursor_o){
  const int* cnt = blockIdx.x ? cnt_o : cnt_s;
  int* start  = blockIdx.x ? start_o  : start_s;
  int* cursor = blockIdx.x ? cursor_o : cursor_s;
  __shared__ int ssum[1024];
  int tid = threadIdx.x;
  int base = tid * SCHUNK;
  int local = 0;
  for(int i = 0; i < SCHUNK; i++){ int idx = base + i; if(idx < NNODE) local += cnt[idx]; }
  ssum[tid] = local; __syncthreads();
  for(int off = 1; off < 1024; off <<= 1){
    int v = (tid >= off) ? ssum[tid - off] : 0;
    __syncthreads();
    ssum[tid] += v;
    __syncthreads();
  }
  int run = (tid == 0) ? 0 : ssum[tid - 1];
  for(int i = 0; i < SCHUNK; i++){
    int idx = base + i;
    if(idx < NNODE){ start[idx] = run; cursor[idx] = run; run += cnt[idx]; }
  }
  if(tid == 1023) start[NNODE] = run;
}

// fill both CSR edge lists (first half of grid: s, second: o)
__global__ void k_fill2(const int* srow, const int* ocol, int* cursor_s, int* cursor_o,
                        int* eidx_s, int* eidx_o){
  int half = gridDim.x >> 1;
  bool oside = blockIdx.x >= half;
  int b = oside ? blockIdx.x - half : blockIdx.x;
  int t = b*256 + threadIdx.x;
  if(t >= NTOT) return;
  if(oside){ int pos = atomicAdd(&cursor_o[ocol[t]], 1); eidx_o[pos] = t; }
  else     { int pos = atomicAdd(&cursor_s[srow[t]], 1); eidx_s[pos] = t; }
}

// CSR-based colsum/rowsum: wave per node; 15 atomics/node (r>=1), r=0 -> stripes.
// blocks [0,NSB): s-side (T2 -> rowsum); [NSB,2*NSB): o-side (T1 -> colsum).
__global__ __launch_bounds__(256) void k_csr_sums(const int* start_s, const int* eidx_s,
    const int* start_o, const int* eidx_o, const int* p, const float* T1, const float* T2,
    float* colsum, float* rowsum, float* stripes){
  bool oside = blockIdx.x >= NSB;
  int b = oside ? blockIdx.x - NSB : blockIdx.x;
  const int* start = oside ? start_o : start_s;
  const int* eidx  = oside ? eidx_o  : eidx_s;
  const float* T   = oside ? T1 : T2;
  float* target    = oside ? colsum : rowsum;
  __shared__ float lT[NREL*RPD];
  __shared__ float w0[4];
  int tid = threadIdx.x;
  for(int i = tid; i < NREL*RPD; i += 256) lT[i] = T[i];
  __syncthreads();
  int wave = tid >> 6, lane = tid & 63;
  int node = b*4 + wave;
  int r = lane & 15, quarter = lane >> 4;
  float acc = 0.f;
  int e0 = start[node], e1 = start[node+1];
  for(int e = e0 + quarter; e < e1; e += 4)
    acc += lT[p[eidx[e]]*RPD + r];
  acc += __shfl_xor(acc, 16);
  acc += __shfl_xor(acc, 32);
  if(quarter == 0){
    if(r >= 1){ if(acc != 0.f) atomicAdd(&target[node*r], acc); }
    else w0[wave] = acc;
  }
  __syncthreads();
  if(tid == 0){
    float v = w0[0]+w0[1]+w0[2]+w0[3];
    atomicAdd(&stripes[(oside ? 64 : 0) + (b & 63)], v);
  }
}

// fold the r=0 stripes into rowsum[0] / colsum[0]
__global__ void k_fix(const float* stripes, float* colsum, float* rowsum){
  int tid = threadIdx.x;  // 128 threads = 2 waves
  float v = stripes[tid];
  for(int off = 32; off > 0; off >>= 1) v += __shfl_down(v, off);
  if(tid == 0)  atomicAdd(&rowsum[0], v);
  if(tid == 64) atomicAdd(&colsum[0], v);
}

// layer1, wave-per-source gather: h[s] = relu(bias1 + sum_e sum_r (T1[p][r]/colsum[o*r])*W1[o*r])
__global__ __launch_bounds__(256) void k_h_csr(const int* start, const int* eidx,
    const int* ocol, const int* p, const float* T1, const float* colsum,
    const void* W1, const void* bias1, float* h, const int* flag){
  __shared__ float lT1[NREL*RPD];
  int bf = *flag;
  int tid = threadIdx.x;
  for(int i = tid; i < NREL*RPD; i += 256) lT1[i] = T1[i];
  __syncthreads();
  int wave = tid >> 6, lane = tid & 63;
  int s = blockIdx.x*4 + wave;
  int r = lane >> 2, q = lane & 3;
  float4 acc = {0.f, 0.f, 0.f, 0.f};
  int e0 = start[s], e1 = start[s+1];
  for(int e = e0; e < e1; e++){
    int t = eidx[e];
    int o = ocol[t], pt = p[t];
    int c = o * r;
    float w = lT1[pt*RPD + r] / fmaxf(colsum[c], EPSF);
    float4 f;
    if(bf){
      uint2 u = *((const uint2*)((const char*)W1 + (size_t)c*32) + q);
      unpack2(u.x, f.x, f.y); unpack2(u.y, f.z, f.w);
    } else {
      f = ((const float4*)W1)[(size_t)c*4 + q];
    }
    acc.x += w*f.x; acc.y += w*f.y; acc.z += w*f.z; acc.w += w*f.w;
  }
  for(int m = 4; m < 64; m <<= 1){
    acc.x += __shfl_xor(acc.x, m); acc.y += __shfl_xor(acc.y, m);
    acc.z += __shfl_xor(acc.z, m); acc.w += __shfl_xor(acc.w, m);
  }
  if(r == 0){
    float4 o4;
    o4.x = fmaxf(acc.x + ldf(bias1, q*4+0, bf), 0.f);
    o4.y = fmaxf(acc.y + ldf(bias1, q*4+1, bf), 0.f);
    o4.z = fmaxf(acc.z + ldf(bias1, q*4+2, bf), 0.f);
    o4.w = fmaxf(acc.w + ldf(bias1, q*4+3, bf), 0.f);
    ((float4*)h)[(size_t)s*4 + q] = o4;
  }
}

// phase A: dense E[s][r][:] = sum_e T2[p][r]*h[o]; coalesced store, no atomics.
// r=0 flood -> 64-striped hacc0.
__global__ __launch_bounds__(256) void k_logitsA(const int* start, const int* eidx,
    const int* ocol, const int* p, const float* T2, const float* h,
    float* E, float* hacc0){
  __shared__ float lT2[NREL*RPD];
  __shared__ float sred[4][16];
  int tid = threadIdx.x;
  for(int i = tid; i < NREL*RPD; i += 256) lT2[i] = T2[i];
  __syncthreads();
  int wave = tid >> 6, lane = tid & 63;
  int s = blockIdx.x*4 + wave;
  int r = lane >> 2, q = lane & 3;
  float4 Ev = {0.f, 0.f, 0.f, 0.f};
  int e0 = start[s], e1 = start[s+1];
  for(int e = e0; e < e1; e++){
    int t = eidx[e];
    int o = ocol[t], pt = p[t];
    float sc = lT2[pt*RPD + r];
    float4 hf = ((const float4*)h)[(size_t)o*4 + q];
    Ev.x += sc*hf.x; Ev.y += sc*hf.y; Ev.z += sc*hf.z; Ev.w += sc*hf.w;
  }
  ((float4*)E)[(size_t)s*64 + lane] = Ev;
  if(r == 0){
    sred[wave][q*4+0] = Ev.x; sred[wave][q*4+1] = Ev.y;
    sred[wave][q*4+2] = Ev.z; sred[wave][q*4+3] = Ev.w;
  }
  __syncthreads();
  if(tid < 16){
    float v = sred[0][tid] + sred[1][tid] + sred[2][tid] + sred[3][tid];
    atomicAdd(&hacc0[(blockIdx.x & 63)*16 + tid], v);
  }
}

// phase B: thread per output node; enumerate divisor pairs (r, s=v/r), gather E,
// apply W2^T / rowsum, add bias + r=0 fix, store output. Zero atomics.
__global__ __launch_bounds__(256) void k_logitsB(const float* E, const float* rowsum,
    const void* W2, const void* bias2, const float* hacc0, void* out, const int* flag){
  __shared__ float lW2[15*EMB*NC];
  int bf = *flag;
  int tid = threadIdx.x;
  for(int i = tid; i < 15*EMB*NC; i += 256) lW2[i] = ldf(W2, i, bf);
  __syncthreads();
  int npi = blockIdx.x*256 + tid;
  if(npi >= NNODE) return;
  float acc[NC];
  #pragma unroll
  for(int c = 0; c < NC; c++) acc[c] = ldf(bias2, c, bf);
  #pragma unroll 1
  for(int rpi = 0; rpi < 15; rpi++){
    unsigned v = (unsigned)rpi*NNODE + (unsigned)npi;
    const float* w2 = lW2 + rpi*EMB*NC;
    float inv = 0.f; int got = 0;
    #pragma unroll
    for(int r = 1; r <= 15; r++){
      if(v % (unsigned)r == 0u){
        unsigned s = v / (unsigned)r;
        if(s < NNODE){
          if(!got){ inv = 1.f / fmaxf(rowsum[v], EPSF); got = 1; }
          const float4* Ep = (const float4*)(E + (size_t)s*256 + r*16);
          float4 a = Ep[0], b = Ep[1], c4 = Ep[2], d = Ep[3];
          #pragma unroll
          for(int c = 0; c < NC; c++){
            float g = w2[0*NC+c]*a.x  + w2[1*NC+c]*a.y  + w2[2*NC+c]*a.z  + w2[3*NC+c]*a.w
                    + w2[4*NC+c]*b.x  + w2[5*NC+c]*b.y  + w2[6*NC+c]*b.z  + w2[7*NC+c]*b.w
                    + w2[8*NC+c]*c4.x + w2[9*NC+c]*c4.y + w2[10*NC+c]*c4.z+ w2[11*NC+c]*c4.w
                    + w2[12*NC+c]*d.x + w2[13*NC+c]*d.y + w2[14*NC+c]*d.z + w2[15*NC+c]*d.w;
            acc[c] += inv * g;
          }
        }
      }
    }
  }
  if(npi == 0){  // r=0 flood: W2[0]^T (sum of hacc0 stripes) / rowsum[0]
    float inv = 1.f / fmaxf(rowsum[0], EPSF);
    #pragma unroll 1
    for(int j = 0; j < EMB; j++){
      float hj = 0.f;
      for(int k = 0; k < 64; k++) hj += hacc0[k*16 + j];
      #pragma unroll
      for(int c = 0; c < NC; c++) acc[c] += inv * lW2[j*NC + c] * hj;
    }
  }
  if(bf){
    #pragma unroll
    for(int c = 0; c < NC; c++) ((__hip_bfloat16*)out)[(size_t)npi*NC + c] = __float2bfloat16(acc[c]);
  } else {
    #pragma unroll
    for(int c = 0; c < NC; c++) ((float*)out)[(size_t)npi*NC + c] = acc[c];
  }
}

// ---------- fallback path (small ws): R3's atomic logits + final ----------
__global__ __launch_bounds__(256) void k_logits_csr(const int* start, const int* eidx,
    const int* ocol, const int* p, const float* T2, const float* rowsum,
    const float* h, const void* W2, float* logitsf, float* hacc0, const int* flag){
  __shared__ float lT2[NREL*RPD];
  __shared__ float lW2[RPD*EMB*NC];
  __shared__ float sred[4][16];
  int bf = *flag;
  int tid = threadIdx.x;
  for(int i = tid; i < NREL*RPD; i += 256) lT2[i] = T2[i];
  for(int i = tid; i < RPD*EMB*NC; i += 256) lW2[i] = ldf(W2, i, bf);
  __syncthreads();
  int wave = tid >> 6, lane = tid & 63;
  int s = blockIdx.x*4 + wave;
  int r = lane >> 2, q = lane & 3;
  float4 E = {0.f, 0.f, 0.f, 0.f};
  int e0 = start[s], e1 = start[s+1];
  for(int e = e0; e < e1; e++){
    int t = eidx[e];
    int o = ocol[t], pt = p[t];
    float sc = lT2[pt*RPD + r];
    float4 hf = ((const float4*)h)[(size_t)o*4 + q];
    E.x += sc*hf.x; E.y += sc*hf.y; E.z += sc*hf.z; E.w += sc*hf.w;
  }
  if(r == 0){
    sred[wave][q*4+0] = E.x; sred[wave][q*4+1] = E.y;
    sred[wave][q*4+2] = E.z; sred[wave][q*4+3] = E.w;
  }
  __syncthreads();
  if(tid < 16){
    float v = sred[0][tid] + sred[1][tid] + sred[2][tid] + sred[3][tid];
    atomicAdd(&hacc0[(blockIdx.x & 63)*16 + tid], v);
  }
  if(r > 0 && e1 > e0){
    int v = s * r;
    float inv = 1.f / fmaxf(rowsum[v], EPSF);
    int rpi = v / NNODE;
    int npi = v - rpi*NNODE;
    const float* w2 = lW2 + rpi*EMB*NC + q*4*NC;
    float g[NC];
    #pragma unroll
    for(int c = 0; c < NC; c++)
      g[c] = w2[c]*E.x + w2[NC+c]*E.y + w2[2*NC+c]*E.z + w2[3*NC+c]*E.w;
    #pragma unroll
    for(int c = 0; c < NC; c++){
      g[c] += __shfl_xor(g[c], 1);
      g[c] += __shfl_xor(g[c], 2);
    }
    if(q == 0){
      float* lp = logitsf + (size_t)npi*NC;
      #pragma unroll
      for(int c = 0; c < NC; c++) atomicAdd(&lp[c], inv*g[c]);
    }
  }
}

__global__ void k_final(const float* logitsf, const void* bias2, const void* W2,
    const float* hacc0, const float* rowsum, void* out, const int* flag){
  int bf = *flag;
  int i = blockIdx.x*blockDim.x + threadIdx.x;
  if(i >= NNODE*NC) return;
  int c = i % NC;
  float val = logitsf[i] + ldf(bias2, c, bf);
  if(i < NC){
    float inv = 1.f / fmaxf(rowsum[0], EPSF);
    float g = 0.f;
    for(int j = 0; j < EMB; j++){
      float hj = 0.f;
      for(int k = 0; k < 64; k++) hj += hacc0[k*16 + j];
      g += ldf(W2, j*NC + c, bf) * hj;
    }
    val += inv * g;
  }
  if(bf) ((__hip_bfloat16*)out)[i] = __float2bfloat16(val);
  else   ((float*)out)[i] = val;
}

extern "C" void kernel_launch(void* const* d_in, const int* in_sizes, int n_in,
                              void* d_out, int out_size, void* d_ws, size_t ws_size,
                              hipStream_t stream){
  const void* nhots = d_in[0];
  const int* hrow = (const int*)d_in[1];   // hrow[t<NT] = s[t]
  const int* vcol = (const int*)d_in[4];   // vcol[t<NT] = o[t]
  const void* Wl1 = d_in[5];
  const void* bl1 = d_in[6];
  const void* Wl2 = d_in[7];
  const void* bl2 = d_in[8];
  const void* W1  = d_in[9];
  const void* bias1 = d_in[10];
  const void* W2  = d_in[11];
  const void* bias2 = d_in[12];

  float* ws = (float*)d_ws;
  int*   flag    = (int*)ws;                  // 16
  float* T1      = ws + 16;                   // 800
  float* T2      = T1 + 800;                  // 800
  float* colsum  = T2 + 800;                  // 800000  -- zero region start
  float* rowsum  = colsum + 800000;           // 800000
  float* hacc0   = rowsum + 800000;           // 1024
  int*   cnt_s   = (int*)(hacc0 + 1024);      // 50000
  int*   cnt_o   = cnt_s + 50000;             // 50000
  float* stripes = (float*)(cnt_o + 50000);   // 128     -- zero region end
  float* h       = stripes + 128;             // 800000
  int*   p       = (int*)(h + 800000);        // 300000
  int*   start_s = p + 300000;                // 50001
  int*   cursor_s= start_s + 50001;           // 50000
  int*   eidx_s  = cursor_s + 50000;          // 300000
  int*   start_o = eidx_s + 300000;           // 50001
  int*   cursor_o= start_o + 50001;           // 50000
  int*   eidx_o  = cursor_o + 50000;          // 300000
  float* tail    = (float*)(eidx_o + 300000); // E (12.8M) or logitsf (500K)
  tail = (float*)(((uintptr_t)tail + 15) & ~(uintptr_t)15);
  bool big = ((char*)tail - (char*)d_ws) + 12800000ull*4 <= ws_size;

  k_detect<<<1, 1024, 0, stream>>>((const unsigned*)nhots, flag);
  k_zero<<<2048, 256, 0, stream>>>(colsum, 1701152L);
  k_tables<<<1, 128, 0, stream>>>(Wl1, bl1, Wl2, bl2, T1, T2, flag);

  const int nblk = (NTOT + 255) / 256;
  k_argmax<<<nblk, 256, 0, stream>>>(nhots, hrow, vcol, p, cnt_s, cnt_o, flag);
  k_scan2<<<2, 1024, 0, stream>>>(cnt_s, start_s, cursor_s, cnt_o, start_o, cursor_o);
  k_fill2<<<2*nblk, 256, 0, stream>>>(hrow, vcol, cursor_s, cursor_o, eidx_s, eidx_o);
  k_csr_sums<<<2*NSB, 256, 0, stream>>>(start_s, eidx_s, start_o, eidx_o, p, T1, T2,
                                        colsum, rowsum, stripes);
  k_fix<<<1, 128, 0, stream>>>(stripes, colsum, rowsum);
  k_h_csr<<<NSB, 256, 0, stream>>>(start_s, eidx_s, vcol, p, T1, colsum, W1, bias1, h, flag);

  if(big){
    k_logitsA<<<NSB, 256, 0, stream>>>(start_s, eidx_s, vcol, p, T2, h, tail, hacc0);
    k_logitsB<<<(NNODE + 255)/256, 256, 0, stream>>>(tail, rowsum, W2, bias2, hacc0, d_out, flag);
  } else {
    k_zero<<<512, 256, 0, stream>>>(tail, 500000L);
    k_logits_csr<<<NSB, 256, 0, stream>>>(start_s, eidx_s, vcol, p, T2, rowsum, h, W2, tail, hacc0, flag);
    k_final<<<(NNODE*NC + 255)/256, 256, 0, stream>>>(tail, bias2, W2, hacc0, rowsum, d_out, flag);
  }
}

// Round 5
// 665.282 us; speedup vs baseline: 4.8003x; 1.2298x over previous
//
#include <hip/hip_runtime.h>
#include <hip/hip_bf16.h>
#include <stdint.h>

#define NTOT  300000
#define NNODE 50000
#define RPD   16
#define NREL  50
#define EMB   16
#define NC    10
#define EPSF  1e-6f

typedef const __hip_bfloat16* bf16p;

__device__ __forceinline__ float b2f(__hip_bfloat16 x){ return __bfloat162float(x); }

__device__ __forceinline__ void unpack2(unsigned u, float& a, float& b){
  a = __uint_as_float(u << 16);
  b = __uint_as_float(u & 0xffff0000u);
}

__device__ __forceinline__ float ldf(const void* p, int i, int bf){
  return bf ? b2f(((bf16p)p)[i]) : ((const float*)p)[i];
}

// ---- dtype detection: fp32 one-hot rows contain ONLY words 0x0 / 0x3F800000.
__global__ void k_detect(const unsigned* nraw, int* flag){
  __shared__ int bad;
  if(threadIdx.x == 0) bad = 0;
  __syncthreads();
  for(int i = threadIdx.x; i < 4096; i += 1024){
    unsigned w = nraw[i];
    if(w != 0u && w != 0x3F800000u) bad = 1;
  }
  __syncthreads();
  if(threadIdx.x == 0) *flag = bad;   // 1 => bf16 mode, 0 => fp32 mode
}

__global__ void k_zero(float* p, long n){
  long i = (long)blockIdx.x*blockDim.x + threadIdx.x;
  long stride = (long)gridDim.x*blockDim.x;
  for(; i < n; i += stride) p[i] = 0.f;
}

// softmax tables: T1/T2[rel][r] = softmax_r(Wl[rel][r] + bl[r])
__global__ void k_tables(const void* Wl1, const void* bl1, const void* Wl2, const void* bl2,
                         float* T1, float* T2, const int* flag){
  int bf = *flag;
  int i = threadIdx.x;
  const void* W = nullptr; const void* bl = nullptr; float* T = nullptr; int row = -1;
  if(i < NREL){ W = Wl1; bl = bl1; T = T1; row = i; }
  else if(i >= 64 && i < 64 + NREL){ W = Wl2; bl = bl2; T = T2; row = i - 64; }
  if(row >= 0){
    float v[RPD]; float m = -1e30f;
    for(int r = 0; r < RPD; r++){
      v[r] = ldf(W, row*RPD + r, bf) + ldf(bl, r, bf);
      m = fmaxf(m, v[r]);
    }
    float s = 0.f;
    for(int r = 0; r < RPD; r++){ v[r] = __expf(v[r] - m); s += v[r]; }
    float inv = 1.f / s;
    for(int r = 0; r < RPD; r++) T[row*RPD + r] = v[r] * inv;
  }
}

// argmax relation per edge + degree histograms for both CSRs
__global__ __launch_bounds__(256) void k_argmax(const void* nhots, const int* srow, const int* ocol,
    int* p, int* cnt_s, int* cnt_o, const int* flag){
  int bf = *flag;
  int t = blockIdx.x*256 + threadIdx.x;
  if(t >= NTOT) return;
  int pt = 0; float best = -1e30f;
  if(bf){
    const unsigned* row = (const unsigned*)nhots + (size_t)t*(NREL/2);
    for(int k = 0; k < NREL/2; k++){
      float a, b; unpack2(row[k], a, b);
      if(a > best){ best = a; pt = 2*k;   }
      if(b > best){ best = b; pt = 2*k+1; }
    }
  } else {
    const uint2* row = (const uint2*)((const float*)nhots + (size_t)t*NREL);
    for(int k = 0; k < NREL/2; k++){
      uint2 u = row[k];
      float a = __uint_as_float(u.x), b = __uint_as_float(u.y);
      if(a > best){ best = a; pt = 2*k;   }
      if(b > best){ best = b; pt = 2*k+1; }
    }
  }
  p[t] = pt;
  atomicAdd(&cnt_s[srow[t]], 1);
  atomicAdd(&cnt_o[ocol[t]], 1);
}

// two independent single-block exclusive scans (block 0: s-side, block 1: o-side)
#define SCHUNK 49
__global__ __launch_bounds__(1024) void k_scan2(const int* cnt_s, int* start_s, int* cursor_s,
                                                const int* cnt_o, int* start_o, int* cursor_o){
  const int* cnt = blockIdx.x ? cnt_o : cnt_s;
  int* start  = blockIdx.x ? start_o  : start_s;
  int* cursor = blockIdx.x ? cursor_o : cursor_s;
  __shared__ int ssum[1024];
  int tid = threadIdx.x;
  int base = tid * SCHUNK;
  int local = 0;
  for(int i = 0; i < SCHUNK; i++){ int idx = base + i; if(idx < NNODE) local += cnt[idx]; }
  ssum[tid] = local; __syncthreads();
  for(int off = 1; off < 1024; off <<= 1){
    int v = (tid >= off) ? ssum[tid - off] : 0;
    __syncthreads();
    ssum[tid] += v;
    __syncthreads();
  }
  int run = (tid == 0) ? 0 : ssum[tid - 1];
  for(int i = 0; i < SCHUNK; i++){
    int idx = base + i;
    if(idx < NNODE){ start[idx] = run; cursor[idx] = run; run += cnt[idx]; }
  }
  if(tid == 1023) start[NNODE] = run;
}

// fill both CSR edge lists; record each edge's s-CSR position (pos_s)
__global__ void k_fill2(const int* srow, const int* ocol, int* cursor_s, int* cursor_o,
                        int* eidx_s, int* pos_s, int* eidx_o){
  int half = gridDim.x >> 1;
  bool oside = blockIdx.x >= half;
  int b = oside ? blockIdx.x - half : blockIdx.x;
  int t = b*256 + threadIdx.x;
  if(t >= NTOT) return;
  if(oside){ int pos = atomicAdd(&cursor_o[ocol[t]], 1); eidx_o[pos] = t; }
  else     { int pos = atomicAdd(&cursor_s[srow[t]], 1); eidx_s[pos] = t; pos_s[t] = pos; }
}

// dense per-node sums: S1[o][r] = sum_{edges of o} T1[p][r];  S2[s][r] = sum T2[p][r].
// No atomics except 64-striped r=0 flood partials.
// floodS[0..63]: o-side (for colsum[0]); floodS[64..127]: s-side (for rowsum[0]).
__global__ __launch_bounds__(256) void k_S12(const int* start_s, const int* eidx_s,
    const int* start_o, const int* eidx_o, const int* p, const float* T1, const float* T2,
    float* S1, float* S2, float* floodS){
  int G = gridDim.x >> 1;
  bool oside = blockIdx.x >= G;
  int b = oside ? blockIdx.x - G : blockIdx.x;
  const int* start = oside ? start_o : start_s;
  const int* eidx  = oside ? eidx_o  : eidx_s;
  const float* T   = oside ? T1 : T2;
  float* S         = oside ? S1 : S2;
  __shared__ float lT[NREL*RPD];
  __shared__ float w0[4];
  int tid = threadIdx.x;
  for(int i = tid; i < NREL*RPD; i += 256) lT[i] = T[i];
  __syncthreads();
  int wave = tid >> 6, lane = tid & 63;
  int r = lane & 15, quarter = lane >> 4;
  float flood = 0.f;
  for(int node = b*4 + wave; node < NNODE; node += G*4){
    float acc = 0.f;
    int e0 = start[node], e1 = start[node+1];
    for(int e = e0 + quarter; e < e1; e += 4)
      acc += lT[p[eidx[e]]*RPD + r];
    acc += __shfl_xor(acc, 16);
    acc += __shfl_xor(acc, 32);
    if(quarter == 0){
      S[node*RPD + r] = acc;
      if(r == 0) flood += acc;
    }
  }
  if(lane == 0) w0[wave] = flood;
  __syncthreads();
  if(tid == 0)
    atomicAdd(&floodS[(oside ? 0 : 64) + (b & 63)], w0[0]+w0[1]+w0[2]+w0[3]);
}

// colsum[v] = sum_{r=1..15, r|v, v/r<N} S1[v/r][r]; v==0 also gets the r=0 flood.
__global__ __launch_bounds__(256) void k_colsum(const float* S1, const float* floodS, float* colsum){
  int stride = gridDim.x*256;
  for(int v = blockIdx.x*256 + threadIdx.x; v < NNODE*RPD; v += stride){
    float acc = 0.f;
    #pragma unroll
    for(int r = 1; r <= 15; r++){
      if(v % (unsigned)r == 0u){
        int s = (unsigned)v / (unsigned)r;
        if(s < NNODE) acc += S1[s*RPD + r];
      }
    }
    if(v == 0){
      float f = 0.f;
      for(int k = 0; k < 64; k++) f += floodS[k];
      acc += f;
    }
    colsum[v] = acc;
  }
}

// layer1 o-side: per object o, load W1 rows {o*r} once; per edge write
// C[pos_s[t]][:] = sum_r (T1[p_t][r]/colsum[o*r]) * W1[o*r][:]. No atomics.
__global__ __launch_bounds__(256) void k_hC(const int* start_o, const int* eidx_o,
    const int* pos_s, const int* p, const float* T1, const float* colsum,
    const void* W1, float* C, const int* flag){
  __shared__ float lT1[NREL*RPD];
  int bf = *flag;
  int tid = threadIdx.x;
  for(int i = tid; i < NREL*RPD; i += 256) lT1[i] = T1[i];
  __syncthreads();
  int wave = tid >> 6, lane = tid & 63;
  int r = lane >> 2, q = lane & 3;
  int wstride = gridDim.x * 4;
  for(int o = blockIdx.x*4 + wave; o < NNODE; o += wstride){
    int e0 = start_o[o], e1 = start_o[o+1];
    if(e0 == e1) continue;
    int c = o * r;
    float inv = 1.f / fmaxf(colsum[c], EPSF);
    float4 w;
    if(bf){
      uint2 u = *((const uint2*)((const char*)W1 + (size_t)c*32) + q);
      unpack2(u.x, w.x, w.y); unpack2(u.y, w.z, w.w);
    } else {
      w = ((const float4*)W1)[(size_t)c*4 + q];
    }
    w.x *= inv; w.y *= inv; w.z *= inv; w.w *= inv;
    for(int e = e0; e < e1; e++){
      int t = eidx_o[e];
      float sc = lT1[p[t]*RPD + r];
      float4 cv; cv.x = sc*w.x; cv.y = sc*w.y; cv.z = sc*w.z; cv.w = sc*w.w;
      for(int m = 4; m < 64; m <<= 1){
        cv.x += __shfl_xor(cv.x, m); cv.y += __shfl_xor(cv.y, m);
        cv.z += __shfl_xor(cv.z, m); cv.w += __shfl_xor(cv.w, m);
      }
      if(r == 0)
        ((float4*)C)[(size_t)pos_s[t]*4 + q] = cv;
    }
  }
}

// h[s] = relu(bias1 + contiguous segment sum of C). Thread per (s, emb-quad).
__global__ void k_hsum(const int* start_s, const float* C, const void* bias1,
                       float* h, const int* flag){
  int bf = *flag;
  int id = blockIdx.x*256 + threadIdx.x;
  if(id >= NNODE*4) return;
  int s = id >> 2, q = id & 3;
  int e0 = start_s[s], e1 = start_s[s+1];
  float4 acc = {0.f,0.f,0.f,0.f};
  for(int e = e0; e < e1; e++){
    float4 c = ((const float4*)C)[(size_t)e*4 + q];
    acc.x += c.x; acc.y += c.y; acc.z += c.z; acc.w += c.w;
  }
  float4 o4;
  o4.x = fmaxf(acc.x + ldf(bias1, q*4+0, bf), 0.f);
  o4.y = fmaxf(acc.y + ldf(bias1, q*4+1, bf), 0.f);
  o4.z = fmaxf(acc.z + ldf(bias1, q*4+2, bf), 0.f);
  o4.w = fmaxf(acc.w + ldf(bias1, q*4+3, bf), 0.f);
  ((float4*)h)[(size_t)s*4 + q] = o4;
}

// dense E[s][r][:] = sum_{edges of s} T2[p][r]*h[o]; coalesced stores, no atomics.
// r=0 flood partials -> 64x16 striped floodE.
__global__ __launch_bounds__(256) void k_E(const int* start_s, const int* eidx_s,
    const int* ocol, const int* p, const float* T2, const float* h,
    float* E, float* floodE){
  __shared__ float lT2[NREL*RPD];
  __shared__ float sred[4][16];
  int tid = threadIdx.x;
  for(int i = tid; i < NREL*RPD; i += 256) lT2[i] = T2[i];
  __syncthreads();
  int wave = tid >> 6, lane = tid & 63;
  int r = lane >> 2, q = lane & 3;
  float4 fl = {0.f,0.f,0.f,0.f};
  int wstride = gridDim.x*4;
  for(int s = blockIdx.x*4 + wave; s < NNODE; s += wstride){
    float4 Ev = {0.f,0.f,0.f,0.f};
    int e0 = start_s[s], e1 = start_s[s+1];
    for(int e = e0; e < e1; e++){
      int t = eidx_s[e];
      int o = ocol[t];
      float sc = lT2[p[t]*RPD + r];
      float4 hf = ((const float4*)h)[(size_t)o*4 + q];
      Ev.x += sc*hf.x; Ev.y += sc*hf.y; Ev.z += sc*hf.z; Ev.w += sc*hf.w;
    }
    ((float4*)E)[(size_t)s*64 + lane] = Ev;
    if(r == 0){ fl.x += Ev.x; fl.y += Ev.y; fl.z += Ev.z; fl.w += Ev.w; }
  }
  if(r == 0){
    sred[wave][q*4+0] = fl.x; sred[wave][q*4+1] = fl.y;
    sred[wave][q*4+2] = fl.z; sred[wave][q*4+3] = fl.w;
  }
  __syncthreads();
  if(tid < 16){
    float v = sred[0][tid]+sred[1][tid]+sred[2][tid]+sred[3][tid];
    atomicAdd(&floodE[(blockIdx.x & 63)*16 + tid], v);
  }
}

// thread per output node: enumerate divisors, inline rowsum from S2, W2^T, bias, store.
__global__ __launch_bounds__(256) void k_logitsB(const float* E, const float* S2,
    const void* W2, const void* bias2, const float* floodS, const float* floodE,
    void* out, const int* flag){
  __shared__ float lW2[15*EMB*NC];
  int bf = *flag;
  int tid = threadIdx.x;
  for(int i = tid; i < 15*EMB*NC; i += 256) lW2[i] = ldf(W2, i, bf);
  __syncthreads();
  int npi = blockIdx.x*256 + tid;
  if(npi >= NNODE) return;
  float acc[NC];
  #pragma unroll
  for(int c = 0; c < NC; c++) acc[c] = ldf(bias2, c, bf);
  #pragma unroll 1
  for(int rpi = 0; rpi < 15; rpi++){
    unsigned v = (unsigned)rpi*NNODE + (unsigned)npi;
    float4 ea = {0.f,0.f,0.f,0.f}, eb = ea, ec = ea, ed = ea;
    float rsum = 0.f;
    #pragma unroll
    for(int r = 1; r <= 15; r++){
      if(v % (unsigned)r == 0u){
        unsigned s = v / (unsigned)r;
        if(s < NNODE){
          rsum += S2[s*RPD + r];
          const float4* Ep = (const float4*)(E + (size_t)s*256 + r*16);
          float4 a = Ep[0], b = Ep[1], c4 = Ep[2], d = Ep[3];
          ea.x += a.x; ea.y += a.y; ea.z += a.z; ea.w += a.w;
          eb.x += b.x; eb.y += b.y; eb.z += b.z; eb.w += b.w;
          ec.x += c4.x; ec.y += c4.y; ec.z += c4.z; ec.w += c4.w;
          ed.x += d.x; ed.y += d.y; ed.z += d.z; ed.w += d.w;
        }
      }
    }
    if(rpi == 0 && npi == 0){
      for(int k = 0; k < 64; k++) rsum += floodS[64 + k];
      for(int k = 0; k < 64; k++){
        const float* fE = floodE + k*16;
        ea.x += fE[0];  ea.y += fE[1];  ea.z += fE[2];  ea.w += fE[3];
        eb.x += fE[4];  eb.y += fE[5];  eb.z += fE[6];  eb.w += fE[7];
        ec.x += fE[8];  ec.y += fE[9];  ec.z += fE[10]; ec.w += fE[11];
        ed.x += fE[12]; ed.y += fE[13]; ed.z += fE[14]; ed.w += fE[15];
      }
    }
    float inv = 1.f / fmaxf(rsum, EPSF);
    const float* w2 = lW2 + rpi*EMB*NC;
    #pragma unroll
    for(int c = 0; c < NC; c++){
      float g = w2[0*NC+c]*ea.x  + w2[1*NC+c]*ea.y  + w2[2*NC+c]*ea.z  + w2[3*NC+c]*ea.w
              + w2[4*NC+c]*eb.x  + w2[5*NC+c]*eb.y  + w2[6*NC+c]*eb.z  + w2[7*NC+c]*eb.w
              + w2[8*NC+c]*ec.x  + w2[9*NC+c]*ec.y  + w2[10*NC+c]*ec.z + w2[11*NC+c]*ec.w
              + w2[12*NC+c]*ed.x + w2[13*NC+c]*ed.y + w2[14*NC+c]*ed.z + w2[15*NC+c]*ed.w;
      acc[c] += inv * g;
    }
  }
  if(bf){
    #pragma unroll
    for(int c = 0; c < NC; c++) ((__hip_bfloat16*)out)[(size_t)npi*NC + c] = __float2bfloat16(acc[c]);
  } else {
    #pragma unroll
    for(int c = 0; c < NC; c++) ((float*)out)[(size_t)npi*NC + c] = acc[c];
  }
}

extern "C" void kernel_launch(void* const* d_in, const int* in_sizes, int n_in,
                              void* d_out, int out_size, void* d_ws, size_t ws_size,
                              hipStream_t stream){
  const void* nhots = d_in[0];
  const int* hrow = (const int*)d_in[1];   // hrow[t<NT] = s[t]
  const int* vcol = (const int*)d_in[4];   // vcol[t<NT] = o[t]
  const void* Wl1 = d_in[5];
  const void* bl1 = d_in[6];
  const void* Wl2 = d_in[7];
  const void* bl2 = d_in[8];
  const void* W1  = d_in[9];
  const void* bias1 = d_in[10];
  const void* W2  = d_in[11];
  const void* bias2 = d_in[12];

  float* ws = (float*)d_ws;
  int*   flag    = (int*)ws;                   // 16
  float* T1      = ws + 16;                    // 800
  float* T2      = T1 + 800;                   // 800
  int*   p       = (int*)(T2 + 800);           // 300000
  int*   start_s = p + 300000;                 // 50004
  int*   start_o = start_s + 50004;            // 50004
  int*   eidx_s  = start_o + 50004;            // 300000
  int*   pos_s   = eidx_s + 300000;            // 300000
  int*   eidx_o  = pos_s + 300000;             // 300000
  float* S2      = (float*)(eidx_o + 300000);  // 800000
  float* h       = S2 + 800000;                // 800000
  int*   cnt_s   = (int*)(h + 800000);         // 50000  -- zero region start
  int*   cnt_o   = cnt_s + 50000;              // 50000
  float* floodS  = (float*)(cnt_o + 50000);    // 128
  float* floodE  = floodS + 128;               // 1024   -- zero region end (101152)
  int*   cursor_s= (int*)(floodE + 1024);      // 50000
  int*   cursor_o= cursor_s + 50000;           // 50000
  float* A       = (float*)(cursor_o + 50000); // overlay region (12.8M words)
  float* S1      = A;                          // [S12 .. colsum)
  float* colsum  = A + 800000;                 // [colsum .. hC)
  float* C       = A + 1600000;                // [hC .. hsum)
  float* E       = A;                          // [E .. logitsB) — S1/colsum/C dead

  k_detect<<<1, 1024, 0, stream>>>((const unsigned*)nhots, flag);
  k_zero<<<396, 256, 0, stream>>>((float*)cnt_s, 101152L);
  k_tables<<<1, 128, 0, stream>>>(Wl1, bl1, Wl2, bl2, T1, T2, flag);

  const int nblk = (NTOT + 255) / 256;  // 1172
  k_argmax<<<nblk, 256, 0, stream>>>(nhots, hrow, vcol, p, cnt_s, cnt_o, flag);
  k_scan2<<<2, 1024, 0, stream>>>(cnt_s, start_s, cursor_s, cnt_o, start_o, cursor_o);
  k_fill2<<<2*nblk, 256, 0, stream>>>(hrow, vcol, cursor_s, cursor_o, eidx_s, pos_s, eidx_o);
  k_S12<<<2048, 256, 0, stream>>>(start_s, eidx_s, start_o, eidx_o, p, T1, T2, S1, S2, floodS);
  k_colsum<<<1024, 256, 0, stream>>>(S1, floodS, colsum);
  k_hC<<<1024, 256, 0, stream>>>(start_o, eidx_o, pos_s, p, T1, colsum, W1, C, flag);
  k_hsum<<<(NNODE*4 + 255)/256, 256, 0, stream>>>(start_s, C, bias1, h, flag);
  k_E<<<1024, 256, 0, stream>>>(start_s, eidx_s, vcol, p, T2, h, E, floodE);
  k_logitsB<<<(NNODE + 255)/256, 256, 0, stream>>>(E, S2, W2, bias2, floodS, floodE, d_out, flag);
}

// Round 6
// 619.347 us; speedup vs baseline: 5.1563x; 1.0742x over previous
//
#include <hip/hip_runtime.h>
#include <hip/hip_bf16.h>
#include <stdint.h>

#define NTOT  300000
#define NNODE 50000
#define RPD   16
#define NREL  50
#define EMB   16
#define NC    10
#define EPSF  1e-6f

typedef const __hip_bfloat16* bf16p;

__device__ __forceinline__ float b2f(__hip_bfloat16 x){ return __bfloat162float(x); }

__device__ __forceinline__ void unpack2(unsigned u, float& a, float& b){
  a = __uint_as_float(u << 16);
  b = __uint_as_float(u & 0xffff0000u);
}

__device__ __forceinline__ float ldf(const void* p, int i, int bf){
  return bf ? b2f(((bf16p)p)[i]) : ((const float*)p)[i];
}

// ---- dtype detection: fp32 one-hot rows contain ONLY words 0x0 / 0x3F800000.
__global__ void k_detect(const unsigned* nraw, int* flag){
  __shared__ int bad;
  if(threadIdx.x == 0) bad = 0;
  __syncthreads();
  for(int i = threadIdx.x; i < 4096; i += 1024){
    unsigned w = nraw[i];
    if(w != 0u && w != 0x3F800000u) bad = 1;
  }
  __syncthreads();
  if(threadIdx.x == 0) *flag = bad;   // 1 => bf16 mode, 0 => fp32 mode
}

__global__ void k_zero(float* p, long n){
  long i = (long)blockIdx.x*blockDim.x + threadIdx.x;
  long stride = (long)gridDim.x*blockDim.x;
  for(; i < n; i += stride) p[i] = 0.f;
}

// softmax tables: T1/T2[rel][r] = softmax_r(Wl[rel][r] + bl[r])
__global__ void k_tables(const void* Wl1, const void* bl1, const void* Wl2, const void* bl2,
                         float* T1, float* T2, const int* flag){
  int bf = *flag;
  int i = threadIdx.x;
  const void* W = nullptr; const void* bl = nullptr; float* T = nullptr; int row = -1;
  if(i < NREL){ W = Wl1; bl = bl1; T = T1; row = i; }
  else if(i >= 64 && i < 64 + NREL){ W = Wl2; bl = bl2; T = T2; row = i - 64; }
  if(row >= 0){
    float v[RPD]; float m = -1e30f;
    for(int r = 0; r < RPD; r++){
      v[r] = ldf(W, row*RPD + r, bf) + ldf(bl, r, bf);
      m = fmaxf(m, v[r]);
    }
    float s = 0.f;
    for(int r = 0; r < RPD; r++){ v[r] = __expf(v[r] - m); s += v[r]; }
    float inv = 1.f / s;
    for(int r = 0; r < RPD; r++) T[row*RPD + r] = v[r] * inv;
  }
}

// argmax relation per edge + degree histograms for both CSRs
__global__ __launch_bounds__(256) void k_argmax(const void* nhots, const int* srow, const int* ocol,
    int* p, int* cnt_s, int* cnt_o, const int* flag){
  int bf = *flag;
  int t = blockIdx.x*256 + threadIdx.x;
  if(t >= NTOT) return;
  int pt = 0; float best = -1e30f;
  if(bf){
    const unsigned* row = (const unsigned*)nhots + (size_t)t*(NREL/2);
    for(int k = 0; k < NREL/2; k++){
      float a, b; unpack2(row[k], a, b);
      if(a > best){ best = a; pt = 2*k;   }
      if(b > best){ best = b; pt = 2*k+1; }
    }
  } else {
    const uint2* row = (const uint2*)((const float*)nhots + (size_t)t*NREL);
    for(int k = 0; k < NREL/2; k++){
      uint2 u = row[k];
      float a = __uint_as_float(u.x), b = __uint_as_float(u.y);
      if(a > best){ best = a; pt = 2*k;   }
      if(b > best){ best = b; pt = 2*k+1; }
    }
  }
  p[t] = pt;
  atomicAdd(&cnt_s[srow[t]], 1);
  atomicAdd(&cnt_o[ocol[t]], 1);
}

// two independent single-block exclusive scans (block 0: s-side, block 1: o-side)
#define SCHUNK 49
__global__ __launch_bounds__(1024) void k_scan2(const int* cnt_s, int* start_s, int* cursor_s,
                                                const int* cnt_o, int* start_o, int* cursor_o){
  const int* cnt = blockIdx.x ? cnt_o : cnt_s;
  int* start  = blockIdx.x ? start_o  : start_s;
  int* cursor = blockIdx.x ? cursor_o : cursor_s;
  __shared__ int ssum[1024];
  int tid = threadIdx.x;
  int base = tid * SCHUNK;
  int local = 0;
  for(int i = 0; i < SCHUNK; i++){ int idx = base + i; if(idx < NNODE) local += cnt[idx]; }
  ssum[tid] = local; __syncthreads();
  for(int off = 1; off < 1024; off <<= 1){
    int v = (tid >= off) ? ssum[tid - off] : 0;
    __syncthreads();
    ssum[tid] += v;
    __syncthreads();
  }
  int run = (tid == 0) ? 0 : ssum[tid - 1];
  for(int i = 0; i < SCHUNK; i++){
    int idx = base + i;
    if(idx < NNODE){ start[idx] = run; cursor[idx] = run; run += cnt[idx]; }
  }
  if(tid == 1023) start[NNODE] = run;
}

// fill both CSR edge lists; record each edge's s-CSR position (pos_s)
__global__ void k_fill2(const int* srow, const int* ocol, int* cursor_s, int* cursor_o,
                        int* eidx_s, int* pos_s, int* eidx_o){
  int half = gridDim.x >> 1;
  bool oside = blockIdx.x >= half;
  int b = oside ? blockIdx.x - half : blockIdx.x;
  int t = b*256 + threadIdx.x;
  if(t >= NTOT) return;
  if(oside){ int pos = atomicAdd(&cursor_o[ocol[t]], 1); eidx_o[pos] = t; }
  else     { int pos = atomicAdd(&cursor_s[srow[t]], 1); eidx_s[pos] = t; pos_s[t] = pos; }
}

// dense per-node sums: S1[o][r] = sum_{edges of o} T1[p][r];  S2[s][r] = sum T2[p][r].
// One node per wave. floodS[0..63]: o-side; floodS[64..127]: s-side.
__global__ __launch_bounds__(256) void k_S12(const int* start_s, const int* eidx_s,
    const int* start_o, const int* eidx_o, const int* p, const float* T1, const float* T2,
    float* S1, float* S2, float* floodS){
  int G = gridDim.x >> 1;
  bool oside = blockIdx.x >= G;
  int b = oside ? blockIdx.x - G : blockIdx.x;
  const int* start = oside ? start_o : start_s;
  const int* eidx  = oside ? eidx_o  : eidx_s;
  const float* T   = oside ? T1 : T2;
  float* S         = oside ? S1 : S2;
  __shared__ float lT[NREL*RPD];
  __shared__ float w0[4];
  int tid = threadIdx.x;
  for(int i = tid; i < NREL*RPD; i += 256) lT[i] = T[i];
  __syncthreads();
  int wave = tid >> 6, lane = tid & 63;
  int r = lane & 15, quarter = lane >> 4;
  float flood = 0.f;
  for(int node = b*4 + wave; node < NNODE; node += G*4){
    float acc = 0.f;
    int e0 = start[node], e1 = start[node+1];
    for(int e = e0 + quarter; e < e1; e += 4)
      acc += lT[p[eidx[e]]*RPD + r];
    acc += __shfl_xor(acc, 16);
    acc += __shfl_xor(acc, 32);
    if(quarter == 0){
      S[node*RPD + r] = acc;
      if(r == 0) flood += acc;
    }
  }
  if(lane == 0) w0[wave] = flood;
  __syncthreads();
  if(tid == 0)
    atomicAdd(&floodS[(oside ? 0 : 64) + (b & 63)], w0[0]+w0[1]+w0[2]+w0[3]);
}

// icolsum[v] = 1/max(eps, sum_{r=1..15, r|v, v/r<N} S1[v/r][r]); v==0 adds the r=0 flood.
__global__ __launch_bounds__(256) void k_icolsum(const float* S1, const float* floodS, float* icolsum){
  int stride = gridDim.x*256;
  for(int v = blockIdx.x*256 + threadIdx.x; v < NNODE*RPD; v += stride){
    float acc = 0.f;
    #pragma unroll
    for(int r = 1; r <= 15; r++){
      if(v % (unsigned)r == 0u){
        int s = (unsigned)v / (unsigned)r;
        if(s < NNODE) acc += S1[s*RPD + r];
      }
    }
    if(v == 0){
      float f = 0.f;
      for(int k = 0; k < 64; k++) f += floodS[k];
      acc += f;
    }
    icolsum[v] = 1.f / fmaxf(acc, EPSF);
  }
}

// layer1, edge x emb-quad parallel (no shuffles, no atomics):
// C[pos_s[t]][q] = sum_r T1[p_t][r] * icolsum[o*r] * W1[o*r][q-quad]
__global__ __launch_bounds__(256) void k_hC(const int* eidx_o, const int* ocol,
    const int* pos_s, const int* p, const float* T1, const float* icolsum,
    const void* W1, float* C, const int* flag){
  __shared__ float lT1[NREL*RPD];
  int bf = *flag;
  int tid = threadIdx.x;
  for(int i = tid; i < NREL*RPD; i += 256) lT1[i] = T1[i];
  __syncthreads();
  int id = blockIdx.x*256 + tid;
  int e = id >> 2, q = id & 3;
  if(e >= NTOT) return;
  int t  = eidx_o[e];
  int o  = ocol[t];
  int pt = p[t];
  int ps = pos_s[t];
  const float* t1 = lT1 + pt*RPD;
  float4 acc = {0.f,0.f,0.f,0.f};
  #pragma unroll
  for(int r = 0; r < RPD; r++){
    int c = o * r;
    float w = t1[r] * icolsum[c];
    float4 f;
    if(bf){
      uint2 u = *((const uint2*)((const char*)W1 + (size_t)c*32) + q);
      unpack2(u.x, f.x, f.y); unpack2(u.y, f.z, f.w);
    } else {
      f = ((const float4*)W1)[(size_t)c*4 + q];
    }
    acc.x += w*f.x; acc.y += w*f.y; acc.z += w*f.z; acc.w += w*f.w;
  }
  ((float4*)C)[(size_t)ps*4 + q] = acc;
}

// h[s] = relu(bias1 + contiguous segment sum of C). Thread per (s, emb-quad).
__global__ void k_hsum(const int* start_s, const float* C, const void* bias1,
                       float* h, const int* flag){
  int bf = *flag;
  int id = blockIdx.x*256 + threadIdx.x;
  if(id >= NNODE*4) return;
  int s = id >> 2, q = id & 3;
  int e0 = start_s[s], e1 = start_s[s+1];
  float4 acc = {0.f,0.f,0.f,0.f};
  for(int e = e0; e < e1; e++){
    float4 c = ((const float4*)C)[(size_t)e*4 + q];
    acc.x += c.x; acc.y += c.y; acc.z += c.z; acc.w += c.w;
  }
  float4 o4;
  o4.x = fmaxf(acc.x + ldf(bias1, q*4+0, bf), 0.f);
  o4.y = fmaxf(acc.y + ldf(bias1, q*4+1, bf), 0.f);
  o4.z = fmaxf(acc.z + ldf(bias1, q*4+2, bf), 0.f);
  o4.w = fmaxf(acc.w + ldf(bias1, q*4+3, bf), 0.f);
  ((float4*)h)[(size_t)s*4 + q] = o4;
}

// dense E[s][r][:] = sum_{edges of s} T2[p][r]*h[o]; coalesced stores, no atomics.
// r=0 flood partials -> 64x16 striped floodE.
__global__ __launch_bounds__(256) void k_E(const int* start_s, const int* eidx_s,
    const int* ocol, const int* p, const float* T2, const float* h,
    float* E, float* floodE){
  __shared__ float lT2[NREL*RPD];
  __shared__ float sred[4][16];
  int tid = threadIdx.x;
  for(int i = tid; i < NREL*RPD; i += 256) lT2[i] = T2[i];
  __syncthreads();
  int wave = tid >> 6, lane = tid & 63;
  int r = lane >> 2, q = lane & 3;
  float4 fl = {0.f,0.f,0.f,0.f};
  int wstride = gridDim.x*4;
  for(int s = blockIdx.x*4 + wave; s < NNODE; s += wstride){
    float4 Ev = {0.f,0.f,0.f,0.f};
    int e0 = start_s[s], e1 = start_s[s+1];
    for(int e = e0; e < e1; e++){
      int t = eidx_s[e];
      int o = ocol[t];
      float sc = lT2[p[t]*RPD + r];
      float4 hf = ((const float4*)h)[(size_t)o*4 + q];
      Ev.x += sc*hf.x; Ev.y += sc*hf.y; Ev.z += sc*hf.z; Ev.w += sc*hf.w;
    }
    ((float4*)E)[(size_t)s*64 + lane] = Ev;
    if(r == 0){ fl.x += Ev.x; fl.y += Ev.y; fl.z += Ev.z; fl.w += Ev.w; }
  }
  if(r == 0){
    sred[wave][q*4+0] = fl.x; sred[wave][q*4+1] = fl.y;
    sred[wave][q*4+2] = fl.z; sred[wave][q*4+3] = fl.w;
  }
  __syncthreads();
  if(tid < 16){
    float v = sred[0][tid]+sred[1][tid]+sred[2][tid]+sred[3][tid];
    atomicAdd(&floodE[(blockIdx.x & 63)*16 + tid], v);
  }
}

// thread per output node: enumerate divisors, inline rowsum from S2, W2^T, bias, store.
__global__ __launch_bounds__(256) void k_logitsB(const float* E, const float* S2,
    const void* W2, const void* bias2, const float* floodS, const float* floodE,
    void* out, const int* flag){
  __shared__ float lW2[15*EMB*NC];
  int bf = *flag;
  int tid = threadIdx.x;
  for(int i = tid; i < 15*EMB*NC; i += 256) lW2[i] = ldf(W2, i, bf);
  __syncthreads();
  int npi = blockIdx.x*256 + tid;
  if(npi >= NNODE) return;
  float acc[NC];
  #pragma unroll
  for(int c = 0; c < NC; c++) acc[c] = ldf(bias2, c, bf);
  #pragma unroll 1
  for(int rpi = 0; rpi < 15; rpi++){
    unsigned v = (unsigned)rpi*NNODE + (unsigned)npi;
    float4 ea = {0.f,0.f,0.f,0.f}, eb = ea, ec = ea, ed = ea;
    float rsum = 0.f;
    #pragma unroll
    for(int r = 1; r <= 15; r++){
      if(v % (unsigned)r == 0u){
        unsigned s = v / (unsigned)r;
        if(s < NNODE){
          rsum += S2[s*RPD + r];
          const float4* Ep = (const float4*)(E + (size_t)s*256 + r*16);
          float4 a = Ep[0], b = Ep[1], c4 = Ep[2], d = Ep[3];
          ea.x += a.x; ea.y += a.y; ea.z += a.z; ea.w += a.w;
          eb.x += b.x; eb.y += b.y; eb.z += b.z; eb.w += b.w;
          ec.x += c4.x; ec.y += c4.y; ec.z += c4.z; ec.w += c4.w;
          ed.x += d.x; ed.y += d.y; ed.z += d.z; ed.w += d.w;
        }
      }
    }
    if(rpi == 0 && npi == 0){
      for(int k = 0; k < 64; k++) rsum += floodS[64 + k];
      for(int k = 0; k < 64; k++){
        const float* fE = floodE + k*16;
        ea.x += fE[0];  ea.y += fE[1];  ea.z += fE[2];  ea.w += fE[3];
        eb.x += fE[4];  eb.y += fE[5];  eb.z += fE[6];  eb.w += fE[7];
        ec.x += fE[8];  ec.y += fE[9];  ec.z += fE[10]; ec.w += fE[11];
        ed.x += fE[12]; ed.y += fE[13]; ed.z += fE[14]; ed.w += fE[15];
      }
    }
    float inv = 1.f / fmaxf(rsum, EPSF);
    const float* w2 = lW2 + rpi*EMB*NC;
    #pragma unroll
    for(int c = 0; c < NC; c++){
      float g = w2[0*NC+c]*ea.x  + w2[1*NC+c]*ea.y  + w2[2*NC+c]*ea.z  + w2[3*NC+c]*ea.w
              + w2[4*NC+c]*eb.x  + w2[5*NC+c]*eb.y  + w2[6*NC+c]*eb.z  + w2[7*NC+c]*eb.w
              + w2[8*NC+c]*ec.x  + w2[9*NC+c]*ec.y  + w2[10*NC+c]*ec.z + w2[11*NC+c]*ec.w
              + w2[12*NC+c]*ed.x + w2[13*NC+c]*ed.y + w2[14*NC+c]*ed.z + w2[15*NC+c]*ed.w;
      acc[c] += inv * g;
    }
  }
  if(bf){
    #pragma unroll
    for(int c = 0; c < NC; c++) ((__hip_bfloat16*)out)[(size_t)npi*NC + c] = __float2bfloat16(acc[c]);
  } else {
    #pragma unroll
    for(int c = 0; c < NC; c++) ((float*)out)[(size_t)npi*NC + c] = acc[c];
  }
}

extern "C" void kernel_launch(void* const* d_in, const int* in_sizes, int n_in,
                              void* d_out, int out_size, void* d_ws, size_t ws_size,
                              hipStream_t stream){
  const void* nhots = d_in[0];
  const int* hrow = (const int*)d_in[1];   // hrow[t<NT] = s[t]
  const int* vcol = (const int*)d_in[4];   // vcol[t<NT] = o[t]
  const void* Wl1 = d_in[5];
  const void* bl1 = d_in[6];
  const void* Wl2 = d_in[7];
  const void* bl2 = d_in[8];
  const void* W1  = d_in[9];
  const void* bias1 = d_in[10];
  const void* W2  = d_in[11];
  const void* bias2 = d_in[12];

  float* ws = (float*)d_ws;
  int*   flag    = (int*)ws;                   // 16
  float* T1      = ws + 16;                    // 800
  float* T2      = T1 + 800;                   // 800
  int*   p       = (int*)(T2 + 800);           // 300000
  int*   start_s = p + 300000;                 // 50004
  int*   start_o = start_s + 50004;            // 50004
  int*   eidx_s  = start_o + 50004;            // 300000
  int*   pos_s   = eidx_s + 300000;            // 300000
  int*   eidx_o  = pos_s + 300000;             // 300000
  float* S2      = (float*)(eidx_o + 300000);  // 800000
  float* h       = S2 + 800000;                // 800000
  int*   cnt_s   = (int*)(h + 800000);         // 50000  -- zero region start
  int*   cnt_o   = cnt_s + 50000;              // 50000
  float* floodS  = (float*)(cnt_o + 50000);    // 128
  float* floodE  = floodS + 128;               // 1024   -- zero region end (101152)
  int*   cursor_s= (int*)(floodE + 1024);      // 50000
  int*   cursor_o= cursor_s + 50000;           // 50000
  float* A       = (float*)(cursor_o + 50000); // overlay region (12.8M words)
  float* S1      = A;                          // [S12 .. icolsum)
  float* icolsum = A + 800000;                 // [icolsum .. hC)
  float* C       = A + 1600000;                // [hC .. hsum)
  float* E       = A;                          // [E .. logitsB) — S1/icolsum/C dead

  k_detect<<<1, 1024, 0, stream>>>((const unsigned*)nhots, flag);
  k_zero<<<396, 256, 0, stream>>>((float*)cnt_s, 101152L);
  k_tables<<<1, 128, 0, stream>>>(Wl1, bl1, Wl2, bl2, T1, T2, flag);

  const int nblk = (NTOT + 255) / 256;  // 1172
  k_argmax<<<nblk, 256, 0, stream>>>(nhots, hrow, vcol, p, cnt_s, cnt_o, flag);
  k_scan2<<<2, 1024, 0, stream>>>(cnt_s, start_s, cursor_s, cnt_o, start_o, cursor_o);
  k_fill2<<<2*nblk, 256, 0, stream>>>(hrow, vcol, cursor_s, cursor_o, eidx_s, pos_s, eidx_o);
  k_S12<<<25000, 256, 0, stream>>>(start_s, eidx_s, start_o, eidx_o, p, T1, T2, S1, S2, floodS);
  k_icolsum<<<1024, 256, 0, stream>>>(S1, floodS, icolsum);
  k_hC<<<(NTOT*4 + 255)/256, 256, 0, stream>>>(eidx_o, vcol, pos_s, p, T1, icolsum, W1, C, flag);
  k_hsum<<<(NNODE*4 + 255)/256, 256, 0, stream>>>(start_s, C, bias1, h, flag);
  k_E<<<2048, 256, 0, stream>>>(start_s, eidx_s, vcol, p, T2, h, E, floodE);
  k_logitsB<<<(NNODE + 255)/256, 256, 0, stream>>>(E, S2, W2, bias2, floodS, floodE, d_out, flag);
}

// Round 7
// 512.079 us; speedup vs baseline: 6.2364x; 1.2095x over previous
//
#include <hip/hip_runtime.h>
#include <hip/hip_bf16.h>
#include <stdint.h>

#define NTOT  300000
#define NNODE 50000
#define RPD   16
#define NREL  50
#define EMB   16
#define NC    10
#define EPSF  1e-6f
#define SG    49   // scan blocks per side: 49*1024 >= 50000

typedef const __hip_bfloat16* bf16p;

__device__ __forceinline__ float b2f(__hip_bfloat16 x){ return __bfloat162float(x); }

__device__ __forceinline__ void unpack2(unsigned u, float& a, float& b){
  a = __uint_as_float(u << 16);
  b = __uint_as_float(u & 0xffff0000u);
}

__device__ __forceinline__ float ldf(const void* p, int i, int bf){
  return bf ? b2f(((bf16p)p)[i]) : ((const float*)p)[i];
}

// ---- dtype detection: fp32 one-hot rows contain ONLY words 0x0 / 0x3F800000.
__global__ void k_detect(const unsigned* nraw, int* flag){
  __shared__ int bad;
  if(threadIdx.x == 0) bad = 0;
  __syncthreads();
  for(int i = threadIdx.x; i < 4096; i += 1024){
    unsigned w = nraw[i];
    if(w != 0u && w != 0x3F800000u) bad = 1;
  }
  __syncthreads();
  if(threadIdx.x == 0) *flag = bad;   // 1 => bf16 mode, 0 => fp32 mode
}

__global__ void k_zero(float* p, long n){
  long i = (long)blockIdx.x*blockDim.x + threadIdx.x;
  long stride = (long)gridDim.x*blockDim.x;
  for(; i < n; i += stride) p[i] = 0.f;
}

// softmax tables: T1/T2[rel][r] = softmax_r(Wl[rel][r] + bl[r])
__global__ void k_tables(const void* Wl1, const void* bl1, const void* Wl2, const void* bl2,
                         float* T1, float* T2, const int* flag){
  int bf = *flag;
  int i = threadIdx.x;
  const void* W = nullptr; const void* bl = nullptr; float* T = nullptr; int row = -1;
  if(i < NREL){ W = Wl1; bl = bl1; T = T1; row = i; }
  else if(i >= 64 && i < 64 + NREL){ W = Wl2; bl = bl2; T = T2; row = i - 64; }
  if(row >= 0){
    float v[RPD]; float m = -1e30f;
    for(int r = 0; r < RPD; r++){
      v[r] = ldf(W, row*RPD + r, bf) + ldf(bl, r, bf);
      m = fmaxf(m, v[r]);
    }
    float s = 0.f;
    for(int r = 0; r < RPD; r++){ v[r] = __expf(v[r] - m); s += v[r]; }
    float inv = 1.f / s;
    for(int r = 0; r < RPD; r++) T[row*RPD + r] = v[r] * inv;
  }
}

// argmax relation per edge + degree histograms for both CSRs
__global__ __launch_bounds__(256) void k_argmax(const void* nhots, const int* srow, const int* ocol,
    int* p, int* cnt_s, int* cnt_o, const int* flag){
  int bf = *flag;
  int t = blockIdx.x*256 + threadIdx.x;
  if(t >= NTOT) return;
  int pt = 0; float best = -1e30f;
  if(bf){
    const unsigned* row = (const unsigned*)nhots + (size_t)t*(NREL/2);
    for(int k = 0; k < NREL/2; k++){
      float a, b; unpack2(row[k], a, b);
      if(a > best){ best = a; pt = 2*k;   }
      if(b > best){ best = b; pt = 2*k+1; }
    }
  } else {
    const uint2* row = (const uint2*)((const float*)nhots + (size_t)t*NREL);
    for(int k = 0; k < NREL/2; k++){
      uint2 u = row[k];
      float a = __uint_as_float(u.x), b = __uint_as_float(u.y);
      if(a > best){ best = a; pt = 2*k;   }
      if(b > best){ best = b; pt = 2*k+1; }
    }
  }
  p[t] = pt;
  atomicAdd(&cnt_s[srow[t]], 1);
  atomicAdd(&cnt_o[ocol[t]], 1);
}

// ---- 3-phase scan: A) per-block exclusive scan + block sums; B) scan block
// sums (one wave per side) + write totals; C) add offsets, write cursors.
__global__ __launch_bounds__(1024) void k_scanA(const int* cnt_s, const int* cnt_o,
    int* start_s, int* start_o, int* bsum){
  int G = gridDim.x >> 1;
  bool oside = blockIdx.x >= G;
  int b = oside ? blockIdx.x - G : blockIdx.x;
  const int* cnt = oside ? cnt_o : cnt_s;
  int* start = oside ? start_o : start_s;
  __shared__ int sh[1024];
  int tid = threadIdx.x;
  int idx = b*1024 + tid;
  int v = (idx < NNODE) ? cnt[idx] : 0;
  sh[tid] = v;
  __syncthreads();
  for(int off = 1; off < 1024; off <<= 1){
    int n = (tid >= off) ? sh[tid - off] : 0;
    __syncthreads();
    sh[tid] += n;
    __syncthreads();
  }
  if(idx < NNODE) start[idx] = sh[tid] - v;   // block-local exclusive
  if(tid == 1023) bsum[(oside ? G : 0) + b] = sh[1023];
}

__global__ void k_scanB(int* bsum, int* start_s, int* start_o){
  int tid = threadIdx.x;          // 128 = 2 waves; wave0 = s-side, wave1 = o-side
  bool oside = tid >= 64;
  int lane = tid & 63;
  int base = oside ? SG : 0;
  int v = (lane < SG) ? bsum[base + lane] : 0;
  int orig = v;
  for(int off = 1; off < 64; off <<= 1){
    int n = __shfl_up(v, off);
    if(lane >= off) v += n;
  }
  if(lane < SG) bsum[base + lane] = v - orig;  // exclusive block offset
  if(lane == 63){
    if(oside) start_o[NNODE] = v; else start_s[NNODE] = v;
  }
}

__global__ __launch_bounds__(1024) void k_scanC(int* start_s, int* start_o,
    int* cursor_s, int* cursor_o, const int* bsum){
  int G = gridDim.x >> 1;
  bool oside = blockIdx.x >= G;
  int b = oside ? blockIdx.x - G : blockIdx.x;
  int idx = b*1024 + threadIdx.x;
  if(idx >= NNODE) return;
  int ofs = bsum[(oside ? G : 0) + b];
  int* start  = oside ? start_o  : start_s;
  int* cursor = oside ? cursor_o : cursor_s;
  int v = start[idx] + ofs;
  start[idx] = v;
  cursor[idx] = v;
}

// fill both CSR edge lists; record each edge's s-CSR position (pos_s)
__global__ void k_fill2(const int* srow, const int* ocol, int* cursor_s, int* cursor_o,
                        int* eidx_s, int* pos_s, int* eidx_o){
  int half = gridDim.x >> 1;
  bool oside = blockIdx.x >= half;
  int b = oside ? blockIdx.x - half : blockIdx.x;
  int t = b*256 + threadIdx.x;
  if(t >= NTOT) return;
  if(oside){ int pos = atomicAdd(&cursor_o[ocol[t]], 1); eidx_o[pos] = t; }
  else     { int pos = atomicAdd(&cursor_s[srow[t]], 1); eidx_s[pos] = t; pos_s[t] = pos; }
}

// dense per-node sums: S1[o][r] = sum_{edges of o} T1[p][r];  S2[s][r] = sum T2[p][r].
// One node per wave. floodS[0..63]: o-side; floodS[64..127]: s-side.
__global__ __launch_bounds__(256) void k_S12(const int* start_s, const int* eidx_s,
    const int* start_o, const int* eidx_o, const int* p, const float* T1, const float* T2,
    float* S1, float* S2, float* floodS){
  int G = gridDim.x >> 1;
  bool oside = blockIdx.x >= G;
  int b = oside ? blockIdx.x - G : blockIdx.x;
  const int* start = oside ? start_o : start_s;
  const int* eidx  = oside ? eidx_o  : eidx_s;
  const float* T   = oside ? T1 : T2;
  float* S         = oside ? S1 : S2;
  __shared__ float lT[NREL*RPD];
  __shared__ float w0[4];
  int tid = threadIdx.x;
  for(int i = tid; i < NREL*RPD; i += 256) lT[i] = T[i];
  __syncthreads();
  int wave = tid >> 6, lane = tid & 63;
  int r = lane & 15, quarter = lane >> 4;
  float flood = 0.f;
  for(int node = b*4 + wave; node < NNODE; node += G*4){
    float acc = 0.f;
    int e0 = start[node], e1 = start[node+1];
    for(int e = e0 + quarter; e < e1; e += 4)
      acc += lT[p[eidx[e]]*RPD + r];
    acc += __shfl_xor(acc, 16);
    acc += __shfl_xor(acc, 32);
    if(quarter == 0){
      S[node*RPD + r] = acc;
      if(r == 0) flood += acc;
    }
  }
  if(lane == 0) w0[wave] = flood;
  __syncthreads();
  if(tid == 0)
    atomicAdd(&floodS[(oside ? 0 : 64) + (b & 63)], w0[0]+w0[1]+w0[2]+w0[3]);
}

// icolsum[v] = 1/max(eps, sum_{r=1..15, r|v, v/r<N} S1[v/r][r]); v==0 adds the r=0 flood.
__global__ __launch_bounds__(256) void k_icolsum(const float* S1, const float* floodS, float* icolsum){
  int stride = gridDim.x*256;
  for(int v = blockIdx.x*256 + threadIdx.x; v < NNODE*RPD; v += stride){
    float acc = 0.f;
    #pragma unroll
    for(int r = 1; r <= 15; r++){
      if(v % (unsigned)r == 0u){
        int s = (unsigned)v / (unsigned)r;
        if(s < NNODE) acc += S1[s*RPD + r];
      }
    }
    if(v == 0){
      float f = 0.f;
      for(int k = 0; k < 64; k++) f += floodS[k];
      acc += f;
    }
    icolsum[v] = 1.f / fmaxf(acc, EPSF);
  }
}

// layer1, edge x emb-quad parallel (no shuffles, no atomics):
// C[pos_s[t]][q] = sum_r T1[p_t][r] * icolsum[o*r] * W1[o*r][q-quad]
__global__ __launch_bounds__(256) void k_hC(const int* eidx_o, const int* ocol,
    const int* pos_s, const int* p, const float* T1, const float* icolsum,
    const void* W1, float* C, const int* flag){
  __shared__ float lT1[NREL*RPD];
  int bf = *flag;
  int tid = threadIdx.x;
  for(int i = tid; i < NREL*RPD; i += 256) lT1[i] = T1[i];
  __syncthreads();
  int id = blockIdx.x*256 + tid;
  int e = id >> 2, q = id & 3;
  if(e >= NTOT) return;
  int t  = eidx_o[e];
  int o  = ocol[t];
  int pt = p[t];
  int ps = pos_s[t];
  const float* t1 = lT1 + pt*RPD;
  float4 acc = {0.f,0.f,0.f,0.f};
  #pragma unroll
  for(int r = 0; r < RPD; r++){
    int c = o * r;
    float w = t1[r] * icolsum[c];
    float4 f;
    if(bf){
      uint2 u = *((const uint2*)((const char*)W1 + (size_t)c*32) + q);
      unpack2(u.x, f.x, f.y); unpack2(u.y, f.z, f.w);
    } else {
      f = ((const float4*)W1)[(size_t)c*4 + q];
    }
    acc.x += w*f.x; acc.y += w*f.y; acc.z += w*f.z; acc.w += w*f.w;
  }
  ((float4*)C)[(size_t)ps*4 + q] = acc;
}

// h[s] = relu(bias1 + contiguous segment sum of C). Thread per (s, emb-quad).
__global__ void k_hsum(const int* start_s, const float* C, const void* bias1,
                       float* h, const int* flag){
  int bf = *flag;
  int id = blockIdx.x*256 + threadIdx.x;
  if(id >= NNODE*4) return;
  int s = id >> 2, q = id & 3;
  int e0 = start_s[s], e1 = start_s[s+1];
  float4 acc = {0.f,0.f,0.f,0.f};
  for(int e = e0; e < e1; e++){
    float4 c = ((const float4*)C)[(size_t)e*4 + q];
    acc.x += c.x; acc.y += c.y; acc.z += c.z; acc.w += c.w;
  }
  float4 o4;
  o4.x = fmaxf(acc.x + ldf(bias1, q*4+0, bf), 0.f);
  o4.y = fmaxf(acc.y + ldf(bias1, q*4+1, bf), 0.f);
  o4.z = fmaxf(acc.z + ldf(bias1, q*4+2, bf), 0.f);
  o4.w = fmaxf(acc.w + ldf(bias1, q*4+3, bf), 0.f);
  ((float4*)h)[(size_t)s*4 + q] = o4;
}

// dense E[s][r][:] = sum_{edges of s} T2[p][r]*h[o]; coalesced stores, no atomics.
// r=0 flood partials -> 64x16 striped floodE.
__global__ __launch_bounds__(256) void k_E(const int* start_s, const int* eidx_s,
    const int* ocol, const int* p, const float* T2, const float* h,
    float* E, float* floodE){
  __shared__ float lT2[NREL*RPD];
  __shared__ float sred[4][16];
  int tid = threadIdx.x;
  for(int i = tid; i < NREL*RPD; i += 256) lT2[i] = T2[i];
  __syncthreads();
  int wave = tid >> 6, lane = tid & 63;
  int r = lane >> 2, q = lane & 3;
  float4 fl = {0.f,0.f,0.f,0.f};
  int wstride = gridDim.x*4;
  for(int s = blockIdx.x*4 + wave; s < NNODE; s += wstride){
    float4 Ev = {0.f,0.f,0.f,0.f};
    int e0 = start_s[s], e1 = start_s[s+1];
    for(int e = e0; e < e1; e++){
      int t = eidx_s[e];
      int o = ocol[t];
      float sc = lT2[p[t]*RPD + r];
      float4 hf = ((const float4*)h)[(size_t)o*4 + q];
      Ev.x += sc*hf.x; Ev.y += sc*hf.y; Ev.z += sc*hf.z; Ev.w += sc*hf.w;
    }
    ((float4*)E)[(size_t)s*64 + lane] = Ev;
    if(r == 0){ fl.x += Ev.x; fl.y += Ev.y; fl.z += Ev.z; fl.w += Ev.w; }
  }
  if(r == 0){
    sred[wave][q*4+0] = fl.x; sred[wave][q*4+1] = fl.y;
    sred[wave][q*4+2] = fl.z; sred[wave][q*4+3] = fl.w;
  }
  __syncthreads();
  if(tid < 16){
    float v = sred[0][tid]+sred[1][tid]+sred[2][tid]+sred[3][tid];
    atomicAdd(&floodE[(blockIdx.x & 63)*16 + tid], v);
  }
}

// thread per output node: enumerate divisors, inline rowsum from S2, W2^T, bias, store.
__global__ __launch_bounds__(256) void k_logitsB(const float* E, const float* S2,
    const void* W2, const void* bias2, const float* floodS, const float* floodE,
    void* out, const int* flag){
  __shared__ float lW2[15*EMB*NC];
  int bf = *flag;
  int tid = threadIdx.x;
  for(int i = tid; i < 15*EMB*NC; i += 256) lW2[i] = ldf(W2, i, bf);
  __syncthreads();
  int npi = blockIdx.x*256 + tid;
  if(npi >= NNODE) return;
  float acc[NC];
  #pragma unroll
  for(int c = 0; c < NC; c++) acc[c] = ldf(bias2, c, bf);
  #pragma unroll 1
  for(int rpi = 0; rpi < 15; rpi++){
    unsigned v = (unsigned)rpi*NNODE + (unsigned)npi;
    float4 ea = {0.f,0.f,0.f,0.f}, eb = ea, ec = ea, ed = ea;
    float rsum = 0.f;
    #pragma unroll
    for(int r = 1; r <= 15; r++){
      if(v % (unsigned)r == 0u){
        unsigned s = v / (unsigned)r;
        if(s < NNODE){
          rsum += S2[s*RPD + r];
          const float4* Ep = (const float4*)(E + (size_t)s*256 + r*16);
          float4 a = Ep[0], b = Ep[1], c4 = Ep[2], d = Ep[3];
          ea.x += a.x; ea.y += a.y; ea.z += a.z; ea.w += a.w;
          eb.x += b.x; eb.y += b.y; eb.z += b.z; eb.w += b.w;
          ec.x += c4.x; ec.y += c4.y; ec.z += c4.z; ec.w += c4.w;
          ed.x += d.x; ed.y += d.y; ed.z += d.z; ed.w += d.w;
        }
      }
    }
    if(rpi == 0 && npi == 0){
      for(int k = 0; k < 64; k++) rsum += floodS[64 + k];
      for(int k = 0; k < 64; k++){
        const float* fE = floodE + k*16;
        ea.x += fE[0];  ea.y += fE[1];  ea.z += fE[2];  ea.w += fE[3];
        eb.x += fE[4];  eb.y += fE[5];  eb.z += fE[6];  eb.w += fE[7];
        ec.x += fE[8];  ec.y += fE[9];  ec.z += fE[10]; ec.w += fE[11];
        ed.x += fE[12]; ed.y += fE[13]; ed.z += fE[14]; ed.w += fE[15];
      }
    }
    float inv = 1.f / fmaxf(rsum, EPSF);
    const float* w2 = lW2 + rpi*EMB*NC;
    #pragma unroll
    for(int c = 0; c < NC; c++){
      float g = w2[0*NC+c]*ea.x  + w2[1*NC+c]*ea.y  + w2[2*NC+c]*ea.z  + w2[3*NC+c]*ea.w
              + w2[4*NC+c]*eb.x  + w2[5*NC+c]*eb.y  + w2[6*NC+c]*eb.z  + w2[7*NC+c]*eb.w
              + w2[8*NC+c]*ec.x  + w2[9*NC+c]*ec.y  + w2[10*NC+c]*ec.z + w2[11*NC+c]*ec.w
              + w2[12*NC+c]*ed.x + w2[13*NC+c]*ed.y + w2[14*NC+c]*ed.z + w2[15*NC+c]*ed.w;
      acc[c] += inv * g;
    }
  }
  if(bf){
    #pragma unroll
    for(int c = 0; c < NC; c++) ((__hip_bfloat16*)out)[(size_t)npi*NC + c] = __float2bfloat16(acc[c]);
  } else {
    #pragma unroll
    for(int c = 0; c < NC; c++) ((float*)out)[(size_t)npi*NC + c] = acc[c];
  }
}

extern "C" void kernel_launch(void* const* d_in, const int* in_sizes, int n_in,
                              void* d_out, int out_size, void* d_ws, size_t ws_size,
                              hipStream_t stream){
  const void* nhots = d_in[0];
  const int* hrow = (const int*)d_in[1];   // hrow[t<NT] = s[t]
  const int* vcol = (const int*)d_in[4];   // vcol[t<NT] = o[t]
  const void* Wl1 = d_in[5];
  const void* bl1 = d_in[6];
  const void* Wl2 = d_in[7];
  const void* bl2 = d_in[8];
  const void* W1  = d_in[9];
  const void* bias1 = d_in[10];
  const void* W2  = d_in[11];
  const void* bias2 = d_in[12];

  float* ws = (float*)d_ws;
  int*   flag    = (int*)ws;                   // 16
  float* T1      = ws + 16;                    // 800
  float* T2      = T1 + 800;                   // 800
  int*   p       = (int*)(T2 + 800);           // 300000
  int*   start_s = p + 300000;                 // 50004
  int*   start_o = start_s + 50004;            // 50004
  int*   eidx_s  = start_o + 50004;            // 300000
  int*   pos_s   = eidx_s + 300000;            // 300000
  int*   eidx_o  = pos_s + 300000;             // 300000
  float* S2      = (float*)(eidx_o + 300000);  // 800000
  float* h       = S2 + 800000;                // 800000
  int*   cnt_s   = (int*)(h + 800000);         // 50000  -- zero region start
  int*   cnt_o   = cnt_s + 50000;              // 50000
  float* floodS  = (float*)(cnt_o + 50000);    // 128
  float* floodE  = floodS + 128;               // 1024   -- zero region end (101152)
  int*   cursor_s= (int*)(floodE + 1024);      // 50000
  int*   cursor_o= cursor_s + 50000;           // 50000
  int*   bsum    = cursor_o + 50000;           // 128 (2*SG=98 used)
  float* A       = (float*)(bsum + 128);       // overlay region (12.8M words)
  float* S1      = A;                          // [S12 .. icolsum)
  float* icolsum = A + 800000;                 // [icolsum .. hC)
  float* C       = A + 1600000;                // [hC .. hsum)
  float* E       = A;                          // [E .. logitsB) — S1/icolsum/C dead

  k_detect<<<1, 1024, 0, stream>>>((const unsigned*)nhots, flag);
  k_zero<<<396, 256, 0, stream>>>((float*)cnt_s, 101152L);
  k_tables<<<1, 128, 0, stream>>>(Wl1, bl1, Wl2, bl2, T1, T2, flag);

  const int nblk = (NTOT + 255) / 256;  // 1172
  k_argmax<<<nblk, 256, 0, stream>>>(nhots, hrow, vcol, p, cnt_s, cnt_o, flag);
  k_scanA<<<2*SG, 1024, 0, stream>>>(cnt_s, cnt_o, start_s, start_o, bsum);
  k_scanB<<<1, 128, 0, stream>>>(bsum, start_s, start_o);
  k_scanC<<<2*SG, 1024, 0, stream>>>(start_s, start_o, cursor_s, cursor_o, bsum);
  k_fill2<<<2*nblk, 256, 0, stream>>>(hrow, vcol, cursor_s, cursor_o, eidx_s, pos_s, eidx_o);
  k_S12<<<25000, 256, 0, stream>>>(start_s, eidx_s, start_o, eidx_o, p, T1, T2, S1, S2, floodS);
  k_icolsum<<<1024, 256, 0, stream>>>(S1, floodS, icolsum);
  k_hC<<<(NTOT*4 + 255)/256, 256, 0, stream>>>(eidx_o, vcol, pos_s, p, T1, icolsum, W1, C, flag);
  k_hsum<<<(NNODE*4 + 255)/256, 256, 0, stream>>>(start_s, C, bias1, h, flag);
  k_E<<<6250, 256, 0, stream>>>(start_s, eidx_s, vcol, p, T2, h, E, floodE);
  k_logitsB<<<(NNODE + 255)/256, 256, 0, stream>>>(E, S2, W2, bias2, floodS, floodE, d_out, flag);
}

// Round 8
// 501.021 us; speedup vs baseline: 6.3740x; 1.0221x over previous
//
#include <hip/hip_runtime.h>
#include <hip/hip_bf16.h>
#include <stdint.h>

#define NTOT  300000
#define NNODE 50000
#define RPD   16
#define NREL  50
#define EMB   16
#define NC    10
#define EPSF  1e-6f
#define SG    49   // scan blocks per side: 49*1024 >= 50000

typedef const __hip_bfloat16* bf16p;

__device__ __forceinline__ float b2f(__hip_bfloat16 x){ return __bfloat162float(x); }

__device__ __forceinline__ void unpack2(unsigned u, float& a, float& b){
  a = __uint_as_float(u << 16);
  b = __uint_as_float(u & 0xffff0000u);
}

__device__ __forceinline__ float ldf(const void* p, int i, int bf){
  return bf ? b2f(((bf16p)p)[i]) : ((const float*)p)[i];
}

// ---- dtype detection: fp32 one-hot rows contain ONLY words 0x0 / 0x3F800000.
__global__ void k_detect(const unsigned* nraw, int* flag){
  __shared__ int bad;
  if(threadIdx.x == 0) bad = 0;
  __syncthreads();
  for(int i = threadIdx.x; i < 4096; i += 1024){
    unsigned w = nraw[i];
    if(w != 0u && w != 0x3F800000u) bad = 1;
  }
  __syncthreads();
  if(threadIdx.x == 0) *flag = bad;   // 1 => bf16 mode, 0 => fp32 mode
}

__global__ void k_zero(float* p, long n){
  long i = (long)blockIdx.x*blockDim.x + threadIdx.x;
  long stride = (long)gridDim.x*blockDim.x;
  for(; i < n; i += stride) p[i] = 0.f;
}

// softmax tables: T1/T2[rel][r] = softmax_r(Wl[rel][r] + bl[r])
__global__ void k_tables(const void* Wl1, const void* bl1, const void* Wl2, const void* bl2,
                         float* T1, float* T2, const int* flag){
  int bf = *flag;
  int i = threadIdx.x;
  const void* W = nullptr; const void* bl = nullptr; float* T = nullptr; int row = -1;
  if(i < NREL){ W = Wl1; bl = bl1; T = T1; row = i; }
  else if(i >= 64 && i < 64 + NREL){ W = Wl2; bl = bl2; T = T2; row = i - 64; }
  if(row >= 0){
    float v[RPD]; float m = -1e30f;
    for(int r = 0; r < RPD; r++){
      v[r] = ldf(W, row*RPD + r, bf) + ldf(bl, r, bf);
      m = fmaxf(m, v[r]);
    }
    float s = 0.f;
    for(int r = 0; r < RPD; r++){ v[r] = __expf(v[r] - m); s += v[r]; }
    float inv = 1.f / s;
    for(int r = 0; r < RPD; r++) T[row*RPD + r] = v[r] * inv;
  }
}

// argmax relation per edge + degree histograms for both CSRs
__global__ __launch_bounds__(256) void k_argmax(const void* nhots, const int* srow, const int* ocol,
    int* p, int* cnt_s, int* cnt_o, const int* flag){
  int bf = *flag;
  int t = blockIdx.x*256 + threadIdx.x;
  if(t >= NTOT) return;
  int pt = 0; float best = -1e30f;
  if(bf){
    const unsigned* row = (const unsigned*)nhots + (size_t)t*(NREL/2);
    for(int k = 0; k < NREL/2; k++){
      float a, b; unpack2(row[k], a, b);
      if(a > best){ best = a; pt = 2*k;   }
      if(b > best){ best = b; pt = 2*k+1; }
    }
  } else {
    const uint2* row = (const uint2*)((const float*)nhots + (size_t)t*NREL);
    for(int k = 0; k < NREL/2; k++){
      uint2 u = row[k];
      float a = __uint_as_float(u.x), b = __uint_as_float(u.y);
      if(a > best){ best = a; pt = 2*k;   }
      if(b > best){ best = b; pt = 2*k+1; }
    }
  }
  p[t] = pt;
  atomicAdd(&cnt_s[srow[t]], 1);
  atomicAdd(&cnt_o[ocol[t]], 1);
}

// ---- 3-phase scan
__global__ __launch_bounds__(1024) void k_scanA(const int* cnt_s, const int* cnt_o,
    int* start_s, int* start_o, int* bsum){
  int G = gridDim.x >> 1;
  bool oside = blockIdx.x >= G;
  int b = oside ? blockIdx.x - G : blockIdx.x;
  const int* cnt = oside ? cnt_o : cnt_s;
  int* start = oside ? start_o : start_s;
  __shared__ int sh[1024];
  int tid = threadIdx.x;
  int idx = b*1024 + tid;
  int v = (idx < NNODE) ? cnt[idx] : 0;
  sh[tid] = v;
  __syncthreads();
  for(int off = 1; off < 1024; off <<= 1){
    int n = (tid >= off) ? sh[tid - off] : 0;
    __syncthreads();
    sh[tid] += n;
    __syncthreads();
  }
  if(idx < NNODE) start[idx] = sh[tid] - v;   // block-local exclusive
  if(tid == 1023) bsum[(oside ? G : 0) + b] = sh[1023];
}

__global__ void k_scanB(int* bsum, int* start_s, int* start_o){
  int tid = threadIdx.x;          // 128 = 2 waves; wave0 = s-side, wave1 = o-side
  bool oside = tid >= 64;
  int lane = tid & 63;
  int base = oside ? SG : 0;
  int v = (lane < SG) ? bsum[base + lane] : 0;
  int orig = v;
  for(int off = 1; off < 64; off <<= 1){
    int n = __shfl_up(v, off);
    if(lane >= off) v += n;
  }
  if(lane < SG) bsum[base + lane] = v - orig;  // exclusive block offset
  if(lane == 63){
    if(oside) start_o[NNODE] = v; else start_s[NNODE] = v;
  }
}

__global__ __launch_bounds__(1024) void k_scanC(int* start_s, int* start_o,
    int* cursor_s, int* cursor_o, const int* bsum){
  int G = gridDim.x >> 1;
  bool oside = blockIdx.x >= G;
  int b = oside ? blockIdx.x - G : blockIdx.x;
  int idx = b*1024 + threadIdx.x;
  if(idx >= NNODE) return;
  int ofs = bsum[(oside ? G : 0) + b];
  int* start  = oside ? start_o  : start_s;
  int* cursor = oside ? cursor_o : cursor_s;
  int v = start[idx] + ofs;
  start[idx] = v;
  cursor[idx] = v;
}

// fill both CSRs with PACKED edge records (no eidx/pos arrays — consumers read
// coalesced):  rec_s[pos] = o | p<<16   (o < 2^16, p < 64)
//              rec_o[posO] = { pos_s | p<<19, o }   (pos_s < 2^19)
__global__ void k_fill(const int* srow, const int* ocol, const int* p,
                       int* cursor_s, int* cursor_o, int* rec_s, int2* rec_o){
  int t = blockIdx.x*256 + threadIdx.x;
  if(t >= NTOT) return;
  int s = srow[t], o = ocol[t], pt = p[t];
  int pos  = atomicAdd(&cursor_s[s], 1);
  int posO = atomicAdd(&cursor_o[o], 1);
  rec_s[pos] = o | (pt << 16);
  int2 r; r.x = pos | (pt << 19); r.y = o;
  rec_o[posO] = r;
}

// S1[o][r] = sum_{edges of o} T1[p][r]. Wave per node, coalesced rec_o reads.
// r=0 flood partials -> floodSo[64].
__global__ __launch_bounds__(256) void k_S1(const int* start_o, const int2* rec_o,
    const float* T1, float* S1, float* floodSo){
  __shared__ float lT[NREL*RPD];
  __shared__ float w0[4];
  int tid = threadIdx.x;
  for(int i = tid; i < NREL*RPD; i += 256) lT[i] = T1[i];
  __syncthreads();
  int wave = tid >> 6, lane = tid & 63;
  int r = lane & 15, quarter = lane >> 4;
  int node = blockIdx.x*4 + wave;
  float acc = 0.f;
  int e0 = start_o[node], e1 = start_o[node+1];
  for(int e = e0 + quarter; e < e1; e += 4){
    int pt = ((unsigned)rec_o[e].x) >> 19;
    acc += lT[pt*RPD + r];
  }
  acc += __shfl_xor(acc, 16);
  acc += __shfl_xor(acc, 32);
  if(quarter == 0){
    S1[node*RPD + r] = acc;
  }
  if(lane == 0) w0[wave] = acc;   // r==0, quarter==0 value
  __syncthreads();
  if(tid == 0)
    atomicAdd(&floodSo[blockIdx.x & 63], w0[0]+w0[1]+w0[2]+w0[3]);
}

// icolsum[v] = 1/max(eps, sum_{r=1..15, r|v, v/r<N} S1[v/r][r]); v==0 adds the r=0 flood.
__global__ __launch_bounds__(256) void k_icolsum(const float* S1, const float* floodSo, float* icolsum){
  int stride = gridDim.x*256;
  for(int v = blockIdx.x*256 + threadIdx.x; v < NNODE*RPD; v += stride){
    float acc = 0.f;
    #pragma unroll
    for(int r = 1; r <= 15; r++){
      if(v % (unsigned)r == 0u){
        int s = (unsigned)v / (unsigned)r;
        if(s < NNODE) acc += S1[s*RPD + r];
      }
    }
    if(v == 0){
      float f = 0.f;
      for(int k = 0; k < 64; k++) f += floodSo[k];
      acc += f;
    }
    icolsum[v] = 1.f / fmaxf(acc, EPSF);
  }
}

// layer1, edge x emb-quad parallel, fully coalesced record reads:
// C[psx][q] = sum_r T1[pt][r] * icolsum[o*r] * W1[o*r][q-quad]
__global__ __launch_bounds__(256) void k_hC(const int2* rec_o, const float* T1,
    const float* icolsum, const void* W1, float* C, const int* flag){
  __shared__ float lT1[NREL*RPD];
  int bf = *flag;
  int tid = threadIdx.x;
  for(int i = tid; i < NREL*RPD; i += 256) lT1[i] = T1[i];
  __syncthreads();
  int id = blockIdx.x*256 + tid;
  int e = id >> 2, q = id & 3;
  if(e >= NTOT) return;
  int2 rec = rec_o[e];
  int psx = rec.x & 0x7FFFF;
  int pt  = ((unsigned)rec.x) >> 19;
  int o   = rec.y;
  const float* t1 = lT1 + pt*RPD;
  float4 acc = {0.f,0.f,0.f,0.f};
  #pragma unroll
  for(int r = 0; r < RPD; r++){
    int c = o * r;
    float w = t1[r] * icolsum[c];
    float4 f;
    if(bf){
      uint2 u = *((const uint2*)((const char*)W1 + (size_t)c*32) + q);
      unpack2(u.x, f.x, f.y); unpack2(u.y, f.z, f.w);
    } else {
      f = ((const float4*)W1)[(size_t)c*4 + q];
    }
    acc.x += w*f.x; acc.y += w*f.y; acc.z += w*f.z; acc.w += w*f.w;
  }
  ((float4*)C)[(size_t)psx*4 + q] = acc;
}

// h[s] = relu(bias1 + contiguous segment sum of C). Thread per (s, emb-quad).
__global__ void k_hsum(const int* start_s, const float* C, const void* bias1,
                       float* h, const int* flag){
  int bf = *flag;
  int id = blockIdx.x*256 + threadIdx.x;
  if(id >= NNODE*4) return;
  int s = id >> 2, q = id & 3;
  int e0 = start_s[s], e1 = start_s[s+1];
  float4 acc = {0.f,0.f,0.f,0.f};
  for(int e = e0; e < e1; e++){
    float4 c = ((const float4*)C)[(size_t)e*4 + q];
    acc.x += c.x; acc.y += c.y; acc.z += c.z; acc.w += c.w;
  }
  float4 o4;
  o4.x = fmaxf(acc.x + ldf(bias1, q*4+0, bf), 0.f);
  o4.y = fmaxf(acc.y + ldf(bias1, q*4+1, bf), 0.f);
  o4.z = fmaxf(acc.z + ldf(bias1, q*4+2, bf), 0.f);
  o4.w = fmaxf(acc.w + ldf(bias1, q*4+3, bf), 0.f);
  ((float4*)h)[(size_t)s*4 + q] = o4;
}

// E[s][r][:] = sum_{edges of s} T2[p][r]*h[o]  AND  S2[s][r] = sum T2[p][r].
// Wave per node, coalesced rec_s reads; only h[o] is a gather (h = 3.2MB, L2-hot).
// r=0 floods -> floodE[64][16], floodS2[64].
__global__ __launch_bounds__(256) void k_E(const int* start_s, const int* rec_s,
    const float* T2, const float* h, float* E, float* S2,
    float* floodE, float* floodS2){
  __shared__ float lT2[NREL*RPD];
  __shared__ float sred[4][16];
  __shared__ float sred2[4];
  int tid = threadIdx.x;
  for(int i = tid; i < NREL*RPD; i += 256) lT2[i] = T2[i];
  __syncthreads();
  int wave = tid >> 6, lane = tid & 63;
  int r = lane >> 2, q = lane & 3;
  int s = blockIdx.x*4 + wave;
  float4 Ev = {0.f,0.f,0.f,0.f};
  float scs = 0.f;
  int e0 = start_s[s], e1 = start_s[s+1];
  for(int e = e0; e < e1; e++){
    int w = rec_s[e];
    int o = w & 0xFFFF;
    int pt = ((unsigned)w) >> 16;
    float sc = lT2[pt*RPD + r];
    float4 hf = ((const float4*)h)[(size_t)o*4 + q];
    Ev.x += sc*hf.x; Ev.y += sc*hf.y; Ev.z += sc*hf.z; Ev.w += sc*hf.w;
    scs += sc;
  }
  ((float4*)E)[(size_t)s*64 + lane] = Ev;
  if(q == 0) S2[s*RPD + r] = scs;
  if(r == 0){
    sred[wave][q*4+0] = Ev.x; sred[wave][q*4+1] = Ev.y;
    sred[wave][q*4+2] = Ev.z; sred[wave][q*4+3] = Ev.w;
    if(q == 0) sred2[wave] = scs;
  }
  __syncthreads();
  if(tid < 16){
    float v = sred[0][tid]+sred[1][tid]+sred[2][tid]+sred[3][tid];
    atomicAdd(&floodE[(blockIdx.x & 63)*16 + tid], v);
  }
  if(tid == 0)
    atomicAdd(&floodS2[blockIdx.x & 63], sred2[0]+sred2[1]+sred2[2]+sred2[3]);
}

// thread per output node: enumerate divisors, inline rowsum from S2, W2^T, bias, store.
__global__ __launch_bounds__(256) void k_logitsB(const float* E, const float* S2,
    const void* W2, const void* bias2, const float* floodS2, const float* floodE,
    void* out, const int* flag){
  __shared__ float lW2[15*EMB*NC];
  int bf = *flag;
  int tid = threadIdx.x;
  for(int i = tid; i < 15*EMB*NC; i += 256) lW2[i] = ldf(W2, i, bf);
  __syncthreads();
  int npi = blockIdx.x*256 + tid;
  if(npi >= NNODE) return;
  float acc[NC];
  #pragma unroll
  for(int c = 0; c < NC; c++) acc[c] = ldf(bias2, c, bf);
  #pragma unroll 1
  for(int rpi = 0; rpi < 15; rpi++){
    unsigned v = (unsigned)rpi*NNODE + (unsigned)npi;
    float4 ea = {0.f,0.f,0.f,0.f}, eb = ea, ec = ea, ed = ea;
    float rsum = 0.f;
    #pragma unroll
    for(int r = 1; r <= 15; r++){
      if(v % (unsigned)r == 0u){
        unsigned s = v / (unsigned)r;
        if(s < NNODE){
          rsum += S2[s*RPD + r];
          const float4* Ep = (const float4*)(E + (size_t)s*256 + r*16);
          float4 a = Ep[0], b = Ep[1], c4 = Ep[2], d = Ep[3];
          ea.x += a.x; ea.y += a.y; ea.z += a.z; ea.w += a.w;
          eb.x += b.x; eb.y += b.y; eb.z += b.z; eb.w += b.w;
          ec.x += c4.x; ec.y += c4.y; ec.z += c4.z; ec.w += c4.w;
          ed.x += d.x; ed.y += d.y; ed.z += d.z; ed.w += d.w;
        }
      }
    }
    if(rpi == 0 && npi == 0){
      for(int k = 0; k < 64; k++) rsum += floodS2[k];
      for(int k = 0; k < 64; k++){
        const float* fE = floodE + k*16;
        ea.x += fE[0];  ea.y += fE[1];  ea.z += fE[2];  ea.w += fE[3];
        eb.x += fE[4];  eb.y += fE[5];  eb.z += fE[6];  eb.w += fE[7];
        ec.x += fE[8];  ec.y += fE[9];  ec.z += fE[10]; ec.w += fE[11];
        ed.x += fE[12]; ed.y += fE[13]; ed.z += fE[14]; ed.w += fE[15];
      }
    }
    float inv = 1.f / fmaxf(rsum, EPSF);
    const float* w2 = lW2 + rpi*EMB*NC;
    #pragma unroll
    for(int c = 0; c < NC; c++){
      float g = w2[0*NC+c]*ea.x  + w2[1*NC+c]*ea.y  + w2[2*NC+c]*ea.z  + w2[3*NC+c]*ea.w
              + w2[4*NC+c]*eb.x  + w2[5*NC+c]*eb.y  + w2[6*NC+c]*eb.z  + w2[7*NC+c]*eb.w
              + w2[8*NC+c]*ec.x  + w2[9*NC+c]*ec.y  + w2[10*NC+c]*ec.z + w2[11*NC+c]*ec.w
              + w2[12*NC+c]*ed.x + w2[13*NC+c]*ed.y + w2[14*NC+c]*ed.z + w2[15*NC+c]*ed.w;
      acc[c] += inv * g;
    }
  }
  if(bf){
    #pragma unroll
    for(int c = 0; c < NC; c++) ((__hip_bfloat16*)out)[(size_t)npi*NC + c] = __float2bfloat16(acc[c]);
  } else {
    #pragma unroll
    for(int c = 0; c < NC; c++) ((float*)out)[(size_t)npi*NC + c] = acc[c];
  }
}

extern "C" void kernel_launch(void* const* d_in, const int* in_sizes, int n_in,
                              void* d_out, int out_size, void* d_ws, size_t ws_size,
                              hipStream_t stream){
  const void* nhots = d_in[0];
  const int* hrow = (const int*)d_in[1];   // hrow[t<NT] = s[t]
  const int* vcol = (const int*)d_in[4];   // vcol[t<NT] = o[t]
  const void* Wl1 = d_in[5];
  const void* bl1 = d_in[6];
  const void* Wl2 = d_in[7];
  const void* bl2 = d_in[8];
  const void* W1  = d_in[9];
  const void* bias1 = d_in[10];
  const void* W2  = d_in[11];
  const void* bias2 = d_in[12];

  float* ws = (float*)d_ws;
  int*   flag    = (int*)ws;                   // 16
  float* T1      = ws + 16;                    // 800
  float* T2      = T1 + 800;                   // 800
  int*   p       = (int*)(T2 + 800);           // 300000
  int*   rec_s   = p + 300000;                 // 300000
  int*   start_s = rec_s + 300000;             // 50004
  int*   start_o = start_s + 50004;            // 50004
  int*   cursor_s= start_o + 50004;            // 50000
  int*   cursor_o= cursor_s + 50000;           // 50000
  int*   bsum    = cursor_o + 50000;           // 128
  int*   cnt_s   = bsum + 128;                 // 50000  -- zero region start
  int*   cnt_o   = cnt_s + 50000;              // 50000
  float* floodSo = (float*)(cnt_o + 50000);    // 64
  float* floodS2 = floodSo + 64;               // 64
  float* floodE  = floodS2 + 64;               // 1024   -- zero end (101152 words)
  float* S2      = floodE + 1024;              // 800000
  float* h       = S2 + 800000;                // 800000
  float* A       = h + 800000;                 // overlay region (12.8M words)
  float* S1      = A;                          // 800000
  float* icolsum = A + 800000;                 // 800000
  float* C       = A + 1600000;                // 4800000
  int2*  rec_o   = (int2*)(A + 6400000);       // 300000 int2 (600000 words)
  float* E       = A;                          // 12.8M — S1/icolsum/C/rec_o dead by k_E

  k_detect<<<1, 1024, 0, stream>>>((const unsigned*)nhots, flag);
  k_zero<<<396, 256, 0, stream>>>((float*)cnt_s, 101152L);
  k_tables<<<1, 128, 0, stream>>>(Wl1, bl1, Wl2, bl2, T1, T2, flag);

  const int nblk = (NTOT + 255) / 256;  // 1172
  k_argmax<<<nblk, 256, 0, stream>>>(nhots, hrow, vcol, p, cnt_s, cnt_o, flag);
  k_scanA<<<2*SG, 1024, 0, stream>>>(cnt_s, cnt_o, start_s, start_o, bsum);
  k_scanB<<<1, 128, 0, stream>>>(bsum, start_s, start_o);
  k_scanC<<<2*SG, 1024, 0, stream>>>(start_s, start_o, cursor_s, cursor_o, bsum);
  k_fill<<<nblk, 256, 0, stream>>>(hrow, vcol, p, cursor_s, cursor_o, rec_s, rec_o);
  k_S1<<<12500, 256, 0, stream>>>(start_o, rec_o, T1, S1, floodSo);
  k_icolsum<<<1024, 256, 0, stream>>>(S1, floodSo, icolsum);
  k_hC<<<(NTOT*4 + 255)/256, 256, 0, stream>>>(rec_o, T1, icolsum, W1, C, flag);
  k_hsum<<<(NNODE*4 + 255)/256, 256, 0, stream>>>(start_s, C, bias1, h, flag);
  k_E<<<12500, 256, 0, stream>>>(start_s, rec_s, T2, h, E, S2, floodE, floodS2);
  k_logitsB<<<(NNODE + 255)/256, 256, 0, stream>>>(E, S2, W2, bias2, floodS2, floodE, d_out, flag);
}